// Round 1
// baseline (1068.631 us; speedup 1.0000x reference)
//
#include <hip/hip_runtime.h>
#include <hip/hip_bf16.h>
#include <cmath>

// ---------------- problem constants ----------------
constexpr int Nn  = 50000;
constexpr int Ee  = 800000;
constexpr int ET  = Ee + Nn;     // edges + self loops
constexpr int F   = 256;         // H*C
constexpr int DIN = 16;
constexpr int DO  = 32;

// weight element offsets inside the converted-f32 weight block
constexpr int W1O=0,     A1S=4096,  A1D=4352,  B1O=4608,
              W2O=4864,  A2S=70400, A2D=70656, B2O=70912,
              W3O=71168, A3S=79360, A3D=79392, B3O=79424,
              G1O=79456, BE1O=79712,G2O=79968, BE2O=80224,
              WR1O=80480,BR1O=81504,WR2O=81536,BR2O=81728, WTOT=81734;

struct InPtrs { const void* p[22]; };

__device__ __forceinline__ float ld_in(const void* p, int i, int bf){
  if (bf){ unsigned u = (unsigned)((const unsigned short*)p)[i];
           union{unsigned u; float f;} c; c.u = u<<16; return c.f; }
  return ((const float*)p)[i];
}
__device__ __forceinline__ void st_out(void* o, int bf, long i, float v){
  if (bf){ union{float f; unsigned u;} c; c.f=v; unsigned u=c.u;
           unsigned r=(u + 0x7fffu + ((u>>16)&1u))>>16;
           ((unsigned short*)o)[i]=(unsigned short)r; }
  else ((float*)o)[i]=v;
}
__device__ __forceinline__ float wmax64(float v){
  #pragma unroll
  for (int o=32;o;o>>=1) v = fmaxf(v, __shfl_xor(v,o));
  return v;
}
__device__ __forceinline__ float wsum64(float v){
  #pragma unroll
  for (int o=32;o;o>>=1) v += __shfl_xor(v,o);
  return v;
}

// ---------------- dtype detect ----------------
// If x is bf16: both 16-bit halves of each u32 are ~N(0,1) values (|v|<6).
// If x is f32: the LOW half is random mantissa bits -> ~48% have bf16-exponent >= 133 (|v|>=64).
__global__ void k_detect(const unsigned* __restrict__ xr, int* __restrict__ flag){
  __shared__ int cnt;
  if (threadIdx.x==0) cnt=0;
  __syncthreads();
  int bad=0;
  for (int i=threadIdx.x;i<2048;i+=256){
    unsigned lo = xr[i]&0xffffu;
    unsigned ex = (lo>>7)&0xffu;
    if (ex>=133u) bad++;
  }
  atomicAdd(&cnt,bad);
  __syncthreads();
  if (threadIdx.x==0) *flag = (cnt<8) ? 1 : 0;   // 1 = inputs are bf16
}

// ---------------- convert all float inputs to f32 scratch ----------------
__global__ void k_convert(InPtrs ip, float* __restrict__ xf, float* __restrict__ wf,
                          const int* __restrict__ flagp){
  int g = blockIdx.x*256 + threadIdx.x;
  int bf = *flagp;
  if (g < Nn*DIN){ xf[g] = ld_in(ip.p[0], g, bf); return; }
  int t = g - Nn*DIN;
  if (t >= WTOT) return;
  const int SIX[20]={2,3,4,5,6,7,8,9,10,11,12,13,14,15,16,17,18,19,20,21};
  const int SOF[20]={W1O,A1S,A1D,B1O,W2O,A2S,A2D,B2O,W3O,A3S,A3D,B3O,
                     G1O,BE1O,G2O,BE2O,WR1O,BR1O,WR2O,BR2O};
  const int SSZ[20]={4096,256,256,256,65536,256,256,256,8192,32,32,32,
                     256,256,256,256,1024,32,192,6};
  for (int j=0;j<20;j++){
    if (t < SSZ[j]){ wf[SOF[j]+t] = ld_in(ip.p[SIX[j]], t, bf); return; }
    t -= SSZ[j];
  }
}

// ---------------- CSR build (by dst, self-loops appended) ----------------
__global__ void k_count(const int* __restrict__ ei, int* __restrict__ deg){
  int g = blockIdx.x*256 + threadIdx.x;
  if (g < Ee) atomicAdd(&deg[ei[Ee+g]], 1);
}

__global__ void __launch_bounds__(1024) k_scan(int* degpos, int* off){
  __shared__ int s[1024];
  __shared__ int carry;
  int tid = threadIdx.x;
  if (tid==0){ carry=0; off[0]=0; }
  __syncthreads();
  for (int chunk=0; chunk<49; chunk++){
    int i = chunk*1024 + tid;
    int v = (i<Nn) ? degpos[i]+1 : 0;      // +1: self loop
    s[tid]=v; __syncthreads();
    for (int d=1; d<1024; d<<=1){
      int t = (tid>=d) ? s[tid-d] : 0;
      __syncthreads();
      s[tid] += t;
      __syncthreads();
    }
    int incl = s[tid];
    int base = carry;
    if (i<Nn){
      int st = base + incl - v;
      degpos[i] = st;                      // becomes fill cursor
      off[i]    = st;
      if (i==Nn-1) off[Nn] = base + incl;
    }
    __syncthreads();
    if (tid==1023) carry = base + s[1023];
    __syncthreads();
  }
}

__global__ void k_fill(const int* __restrict__ ei, int* __restrict__ cursor,
                       int* __restrict__ csr){
  int g = blockIdx.x*256 + threadIdx.x;
  if (g < Ee){
    int s = ei[g], d = ei[Ee+g];
    int p = atomicAdd(&cursor[d],1);
    csr[p] = s;
  } else if (g < ET){
    int n = g - Ee;
    int p = atomicAdd(&cursor[n],1);
    csr[p] = n;
  }
}

// ---------------- GEMMs (VALU f32, correctness-first) ----------------
__global__ void __launch_bounds__(256) k_gemm1(const float* __restrict__ xf,
                                               const float* __restrict__ W,
                                               float* __restrict__ out){
  __shared__ float Ws[DIN*F];     // 16KB
  __shared__ float xs[64*DIN];    // 4KB
  int row0 = blockIdx.x*64;
  for (int i=threadIdx.x;i<DIN*F;i+=256) Ws[i]=W[i];
  for (int i=threadIdx.x;i<64*DIN;i+=256){
    int row = row0 + (i>>4);
    xs[i] = (row<Nn) ? xf[(long)row*DIN + (i&15)] : 0.f;
  }
  __syncthreads();
  for (int r=0;r<64;r++){
    int row = row0 + r;
    if (row>=Nn) break;
    float a=0.f;
    #pragma unroll
    for (int k=0;k<DIN;k++) a += xs[r*DIN+k]*Ws[k*F+threadIdx.x];
    out[(long)row*F + threadIdx.x] = a;
  }
}

__global__ void __launch_bounds__(256) k_gemm2(const float* __restrict__ Hin,
                                               const float* __restrict__ W,
                                               float* __restrict__ out){
  __shared__ float hs[32*F];      // 32KB
  int row0 = blockIdx.x*32;
  for (int i=threadIdx.x;i<32*F;i+=256){
    int row = row0 + (i>>8);
    hs[i] = (row<Nn) ? Hin[(long)row*F + (i&255)] : 0.f;
  }
  __syncthreads();
  float acc[32];
  #pragma unroll
  for (int r=0;r<32;r++) acc[r]=0.f;
  int j = threadIdx.x;
  #pragma unroll 2
  for (int k=0;k<F;k++){
    float w = W[k*F + j];
    #pragma unroll
    for (int r=0;r<32;r++) acc[r] += hs[r*F+k]*w;
  }
  #pragma unroll
  for (int r=0;r<32;r++){
    int row = row0 + r;
    if (row<Nn) out[(long)row*F + j] = acc[r];
  }
}

__global__ void __launch_bounds__(256) k_gemm3(const float* __restrict__ Hin,
                                               const float* __restrict__ W,
                                               float* __restrict__ out){
  __shared__ float Ws[F*DO];      // 32KB
  for (int i=threadIdx.x;i<F*DO;i+=256) Ws[i]=W[i];
  __syncthreads();
  int col = threadIdx.x&31, rl = threadIdx.x>>5;
  int row0 = blockIdx.x*64;
  for (int it=0; it<8; it++){
    int row = row0 + it*8 + rl;
    if (row<Nn){
      float a=0.f;
      #pragma unroll 4
      for (int k=0;k<F;k++) a += Hin[(long)row*F+k]*Ws[k*DO+col];
      out[(long)row*DO+col]=a;
    }
  }
}

// ---------------- attention scores: as[n][h], ad[n][h] ----------------
__global__ void __launch_bounds__(256) k_asad(const float* __restrict__ Hn,
                                              const float* __restrict__ asw,
                                              const float* __restrict__ adw,
                                              float* __restrict__ as4,
                                              float* __restrict__ ad4){
  int wid = threadIdx.x>>6, lane = threadIdx.x&63;
  int n = blockIdx.x*4 + wid;
  if (n>=Nn) return;
  #pragma unroll
  for (int h=0;h<4;h++){
    float v  = Hn[(long)n*F + h*64 + lane];
    float ps = wsum64(v*asw[h*64+lane]);
    float pd = wsum64(v*adw[h*64+lane]);
    if (lane==0){ as4[n*4+h]=ps; ad4[n*4+h]=pd; }
  }
}

// ---------------- GAT aggregation (wave per dst node) ----------------
__global__ void __launch_bounds__(256) k_agg(const float* __restrict__ Hs,
                                             const float* __restrict__ as4,
                                             const float* __restrict__ ad4,
                                             const float* __restrict__ bias,
                                             const int* __restrict__ off,
                                             const int* __restrict__ csr,
                                             float* __restrict__ out){
  int wid = threadIdx.x>>6, lane = threadIdx.x&63;
  int n = blockIdx.x*4 + wid;
  if (n>=Nn) return;
  int o0=off[n], o1=off[n+1];
  float ad0=ad4[n*4+0], ad1=ad4[n*4+1], ad2=ad4[n*4+2], ad3=ad4[n*4+3];
  float m0=-1e30f,m1=-1e30f,m2=-1e30f,m3=-1e30f;
  for (int e=o0+lane; e<o1; e+=64){
    int s=csr[e];
    float t0=as4[s*4+0]+ad0; t0=t0>0.f?t0:0.2f*t0; m0=fmaxf(m0,t0);
    float t1=as4[s*4+1]+ad1; t1=t1>0.f?t1:0.2f*t1; m1=fmaxf(m1,t1);
    float t2=as4[s*4+2]+ad2; t2=t2>0.f?t2:0.2f*t2; m2=fmaxf(m2,t2);
    float t3=as4[s*4+3]+ad3; t3=t3>0.f?t3:0.2f*t3; m3=fmaxf(m3,t3);
  }
  m0=wmax64(m0); m1=wmax64(m1); m2=wmax64(m2); m3=wmax64(m3);
  float s0=0,s1=0,s2=0,s3=0;
  for (int e=o0+lane; e<o1; e+=64){
    int s=csr[e];
    float t0=as4[s*4+0]+ad0; t0=t0>0.f?t0:0.2f*t0; s0+=expf(t0-m0);
    float t1=as4[s*4+1]+ad1; t1=t1>0.f?t1:0.2f*t1; s1+=expf(t1-m1);
    float t2=as4[s*4+2]+ad2; t2=t2>0.f?t2:0.2f*t2; s2+=expf(t2-m2);
    float t3=as4[s*4+3]+ad3; t3=t3>0.f?t3:0.2f*t3; s3+=expf(t3-m3);
  }
  s0=1.f/(wsum64(s0)+1e-16f); s1=1.f/(wsum64(s1)+1e-16f);
  s2=1.f/(wsum64(s2)+1e-16f); s3=1.f/(wsum64(s3)+1e-16f);
  int hh = lane>>4;
  float mxh = (hh&2) ? ((hh&1)?m3:m2) : ((hh&1)?m1:m0);
  float rdh = (hh&2) ? ((hh&1)?s3:s2) : ((hh&1)?s1:s0);
  float adh = (hh&2) ? ((hh&1)?ad3:ad2) : ((hh&1)?ad1:ad0);
  float a0=0,a1=0,a2=0,a3=0;
  for (int e=o0; e<o1; e++){
    int s=csr[e];
    float t=as4[s*4+hh]+adh; t=t>0.f?t:0.2f*t;
    float w=expf(t-mxh)*rdh;
    const float4 hv = *reinterpret_cast<const float4*>(Hs + (long)s*F + lane*4);
    a0 += w*hv.x; a1 += w*hv.y; a2 += w*hv.z; a3 += w*hv.w;
  }
  int c = lane*4;
  long bo = (long)n*F + c;
  out[bo  ] = a0 + bias[c  ];
  out[bo+1] = a1 + bias[c+1];
  out[bo+2] = a2 + bias[c+2];
  out[bo+3] = a3 + bias[c+3];
}

// ---------------- LayerNorm + ELU ----------------
__global__ void __launch_bounds__(256) k_lnelu(const float* __restrict__ in,
                                               const float* __restrict__ g,
                                               const float* __restrict__ be,
                                               float* __restrict__ out){
  int wid=threadIdx.x>>6, lane=threadIdx.x&63;
  int n = blockIdx.x*4 + wid;
  if (n>=Nn) return;
  const float4 v = *reinterpret_cast<const float4*>(in + (long)n*F + lane*4);
  float s = wsum64(v.x+v.y+v.z+v.w);
  float mu = s*(1.f/256.f);
  float dx=v.x-mu, dy=v.y-mu, dz=v.z-mu, dw=v.w-mu;
  float q = wsum64(dx*dx+dy*dy+dz*dz+dw*dw);
  float r = rsqrtf(q*(1.f/256.f) + 1e-5f);
  int c = lane*4;
  const float4 gv = *reinterpret_cast<const float4*>(g+c);
  const float4 bv = *reinterpret_cast<const float4*>(be+c);
  float y0=dx*r*gv.x+bv.x, y1=dy*r*gv.y+bv.y, y2=dz*r*gv.z+bv.z, y3=dw*r*gv.w+bv.w;
  y0 = y0>0.f?y0:expm1f(y0);
  y1 = y1>0.f?y1:expm1f(y1);
  y2 = y2>0.f?y2:expm1f(y2);
  y3 = y3>0.f?y3:expm1f(y3);
  float4 o4; o4.x=y0; o4.y=y1; o4.z=y2; o4.w=y3;
  *reinterpret_cast<float4*>(out + (long)n*F + c) = o4;
}

// ---------------- layer 3: scores + aggregation (1 head, 32 ch) ----------------
__global__ void __launch_bounds__(256) k_asad3(const float* __restrict__ C3,
                                               const float* __restrict__ asw,
                                               const float* __restrict__ adw,
                                               float* __restrict__ s3,
                                               float* __restrict__ d3){
  int wid=threadIdx.x>>6, lane=threadIdx.x&63;
  int n = blockIdx.x*4 + wid;
  if (n>=Nn) return;
  float v = (lane<32) ? C3[(long)n*DO + lane] : 0.f;
  float wa = (lane<32) ? asw[lane] : 0.f;
  float wd = (lane<32) ? adw[lane] : 0.f;
  float ps = wsum64(v*wa);
  float pd = wsum64(v*wd);
  if (lane==0){ s3[n]=ps; d3[n]=pd; }
}

__global__ void __launch_bounds__(256) k_agg3(const float* __restrict__ C3,
                                              const float* __restrict__ s3,
                                              const float* __restrict__ d3,
                                              const float* __restrict__ b3,
                                              const int* __restrict__ off,
                                              const int* __restrict__ csr,
                                              float* __restrict__ h3f,
                                              void* __restrict__ dout,
                                              const int* __restrict__ flagp){
  int wid=threadIdx.x>>6, lane=threadIdx.x&63;
  int n = blockIdx.x*4 + wid;
  if (n>=Nn) return;
  int bf = *flagp;
  int o0=off[n], o1=off[n+1];
  float adn = d3[n];
  float mx=-1e30f;
  for (int e=o0+lane;e<o1;e+=64){
    float t=s3[csr[e]]+adn; t=t>0.f?t:0.2f*t; mx=fmaxf(mx,t);
  }
  mx=wmax64(mx);
  float sm=0.f;
  for (int e=o0+lane;e<o1;e+=64){
    float t=s3[csr[e]]+adn; t=t>0.f?t:0.2f*t; sm+=expf(t-mx);
  }
  sm=wsum64(sm);
  float rd=1.f/(sm+1e-16f);
  int c=lane&31, half=lane>>5;
  float acc=0.f;
  for (int e0=o0;e0<o1;e0+=2){
    int e=e0+half;
    if (e<o1){
      int s=csr[e];
      float t=s3[s]+adn; t=t>0.f?t:0.2f*t;
      float w=expf(t-mx)*rd;
      acc += w*C3[(long)s*DO+c];
    }
  }
  acc += __shfl_xor(acc,32);
  if (lane<32){
    float v = acc + b3[c];
    h3f[(long)n*DO+c] = v;
    st_out(dout, bf, (long)n*DO+c, v);
  }
}

// ---------------- risk head ----------------
__global__ void __launch_bounds__(256) k_risk(const float* __restrict__ h3f,
                                              const float* __restrict__ wf,
                                              void* __restrict__ dout,
                                              const int* __restrict__ flagp){
  int n = blockIdx.x*256 + threadIdx.x;
  if (n>=Nn) return;
  int bf = *flagp;
  float hv[32];
  #pragma unroll
  for (int k=0;k<32;k++) hv[k]=h3f[(long)n*32+k];
  float t1[32];
  #pragma unroll
  for (int j=0;j<32;j++){
    float s = wf[BR1O+j];
    #pragma unroll
    for (int k=0;k<32;k++) s += hv[k]*wf[WR1O+k*32+j];
    t1[j] = fmaxf(s,0.f);
  }
  #pragma unroll
  for (int o=0;o<6;o++){
    float s = wf[BR2O+o];
    #pragma unroll
    for (int j=0;j<32;j++) s += t1[j]*wf[WR2O+j*6+o];
    float r = 1.f/(1.f+expf(-s));
    st_out(dout, bf, (long)Nn*32 + (long)n*6 + o, r);
  }
}

// ---------------- launcher ----------------
extern "C" void kernel_launch(void* const* d_in, const int* in_sizes, int n_in,
                              void* d_out, int out_size, void* d_ws, size_t ws_size,
                              hipStream_t stream){
  char* base = (char*)d_ws;
  size_t cur = 0;
  auto alloc = [&](size_t bytes)->char*{
    cur = (cur + 255) & ~(size_t)255;
    char* r = base + cur; cur += bytes; return r;
  };
  int*   flag = (int*)  alloc(4);
  float* wf   = (float*)alloc(sizeof(float)*WTOT);
  float* xf   = (float*)alloc(sizeof(float)*(size_t)Nn*DIN);
  int*   off  = (int*)  alloc(sizeof(int)*(Nn+1));
  int*   pos  = (int*)  alloc(sizeof(int)*Nn);
  int*   csr  = (int*)  alloc(sizeof(int)*ET);
  float* A    = (float*)alloc(sizeof(float)*(size_t)Nn*F);
  float* B    = (float*)alloc(sizeof(float)*(size_t)Nn*F);
  float* as4  = (float*)alloc(sizeof(float)*(size_t)Nn*4);
  float* ad4  = (float*)alloc(sizeof(float)*(size_t)Nn*4);
  float* C3b  = (float*)alloc(sizeof(float)*(size_t)Nn*DO);
  float* s3   = (float*)alloc(sizeof(float)*Nn);
  float* d3   = (float*)alloc(sizeof(float)*Nn);
  float* h3f  = (float*)alloc(sizeof(float)*(size_t)Nn*DO);

  const int* ei = (const int*)d_in[1];
  InPtrs ip;
  for (int i=0;i<22;i++) ip.p[i]=d_in[i];

  k_detect<<<1,256,0,stream>>>((const unsigned*)d_in[0], flag);
  {
    int total = Nn*DIN + WTOT;
    k_convert<<<(total+255)/256,256,0,stream>>>(ip, xf, wf, flag);
  }
  (void)hipMemsetAsync(pos, 0, sizeof(int)*Nn, stream);
  k_count<<<(Ee+255)/256,256,0,stream>>>(ei, pos);
  k_scan <<<1,1024,0,stream>>>(pos, off);
  k_fill <<<(ET+255)/256,256,0,stream>>>(ei, pos, csr);

  dim3 wg((Nn+3)/4);
  // layer 1
  k_gemm1<<<(Nn+63)/64,256,0,stream>>>(xf, wf+W1O, A);
  k_asad <<<wg,256,0,stream>>>(A, wf+A1S, wf+A1D, as4, ad4);
  k_agg  <<<wg,256,0,stream>>>(A, as4, ad4, wf+B1O, off, csr, B);
  k_lnelu<<<wg,256,0,stream>>>(B, wf+G1O, wf+BE1O, A);
  // layer 2
  k_gemm2<<<(Nn+31)/32,256,0,stream>>>(A, wf+W2O, B);
  k_asad <<<wg,256,0,stream>>>(B, wf+A2S, wf+A2D, as4, ad4);
  k_agg  <<<wg,256,0,stream>>>(B, as4, ad4, wf+B2O, off, csr, A);
  k_lnelu<<<wg,256,0,stream>>>(A, wf+G2O, wf+BE2O, B);
  // layer 3
  k_gemm3<<<(Nn+63)/64,256,0,stream>>>(B, wf+W3O, C3b);
  k_asad3<<<wg,256,0,stream>>>(C3b, wf+A3S, wf+A3D, s3, d3);
  k_agg3 <<<wg,256,0,stream>>>(C3b, s3, d3, wf+B3O, off, csr, h3f, d_out, flag);
  k_risk <<<(Nn+255)/256,256,0,stream>>>(h3f, wf, d_out, flag);
}

// Round 2
// 776.478 us; speedup vs baseline: 1.3763x; 1.3763x over previous
//
#include <hip/hip_runtime.h>
#include <hip/hip_bf16.h>
#include <cmath>

// ---------------- problem constants ----------------
constexpr int Nn  = 50000;
constexpr int Np  = 50176;       // Nn padded to 256 (MFMA tile tail reads)
constexpr int Ee  = 800000;
constexpr int ET  = Ee + Nn;     // edges + self loops
constexpr int F   = 256;         // H*C
constexpr int DIN = 16;
constexpr int DO  = 32;

// f32 weight block offsets (W2/W3 live separately as bf16 transposed)
constexpr int W1O=0, A1S=4096, A1D=4352, B1O=4608,
              A2S=4864, A2D=5120, B2O=5376,
              A3S=5632, A3D=5664, B3O=5696,
              G1O=5728, BE1O=5984, G2O=6240, BE2O=6496,
              WR1O=6752, BR1O=7776, WR2O=7808, BR2O=8000, WTOT=8006;

struct InPtrs { const void* p[22]; };

typedef __attribute__((ext_vector_type(8))) short short8v;
typedef __attribute__((ext_vector_type(4))) float f32x4;

__device__ __forceinline__ float ld_in(const void* p, int i, int bf){
  if (bf){ unsigned u = (unsigned)((const unsigned short*)p)[i];
           union{unsigned u; float f;} c; c.u = u<<16; return c.f; }
  return ((const float*)p)[i];
}
__device__ __forceinline__ float b2f(unsigned short u){
  union{unsigned u; float f;} c; c.u = ((unsigned)u)<<16; return c.f;
}
__device__ __forceinline__ unsigned short f2b(float f){
  union{float f; unsigned u;} c; c.f=f; unsigned u=c.u;
  return (unsigned short)((u + 0x7fffu + ((u>>16)&1u))>>16);
}
__device__ __forceinline__ void st_out(void* o, int bf, long i, float v){
  if (bf) ((unsigned short*)o)[i] = f2b(v);
  else ((float*)o)[i]=v;
}
__device__ __forceinline__ float wmax64(float v){
  #pragma unroll
  for (int o=32;o;o>>=1) v = fmaxf(v, __shfl_xor(v,o));
  return v;
}
__device__ __forceinline__ float wsum64(float v){
  #pragma unroll
  for (int o=32;o;o>>=1) v += __shfl_xor(v,o);
  return v;
}

// ---------------- dtype detect ----------------
__global__ void k_detect(const unsigned* __restrict__ xr, int* __restrict__ flag){
  __shared__ int cnt;
  if (threadIdx.x==0) cnt=0;
  __syncthreads();
  int bad=0;
  for (int i=threadIdx.x;i<2048;i+=256){
    unsigned lo = xr[i]&0xffffu;
    unsigned ex = (lo>>7)&0xffu;
    if (ex>=133u) bad++;
  }
  atomicAdd(&cnt,bad);
  __syncthreads();
  if (threadIdx.x==0) *flag = (cnt<8) ? 1 : 0;   // 1 = inputs are bf16
}

// ---------------- convert inputs ----------------
__global__ void k_convert(InPtrs ip, float* __restrict__ xf, float* __restrict__ wf,
                          const int* __restrict__ flagp){
  int g = blockIdx.x*256 + threadIdx.x;
  int bf = *flagp;
  if (g < Nn*DIN){ xf[g] = ld_in(ip.p[0], g, bf); return; }
  int t = g - Nn*DIN;
  if (t >= WTOT) return;
  const int SIX[18]={2,3,4,5,7,8,9,11,12,13,14,15,16,17,18,19,20,21};
  const int SOF[18]={W1O,A1S,A1D,B1O,A2S,A2D,B2O,A3S,A3D,B3O,
                     G1O,BE1O,G2O,BE2O,WR1O,BR1O,WR2O,BR2O};
  const int SSZ[18]={4096,256,256,256,256,256,256,32,32,32,
                     256,256,256,256,1024,32,192,6};
  for (int j=0;j<18;j++){
    if (t < SSZ[j]){ wf[SOF[j]+t] = ld_in(ip.p[SIX[j]], t, bf); return; }
    t -= SSZ[j];
  }
}

// transpose W2 [256,256] -> W2T bf16 [N][K]
__global__ void k_w2t(const void* __restrict__ w2, unsigned short* __restrict__ w2t,
                      const int* __restrict__ flagp){
  int g = blockIdx.x*256 + threadIdx.x;
  if (g >= 256*256) return;
  int bf = *flagp;
  int n = g>>8, k = g&255;
  w2t[n*256+k] = f2b(ld_in(w2, k*256+n, bf));
}
// transpose W3 [256,32] -> W3T bf16 [32][256]
__global__ void k_w3t(const void* __restrict__ w3, unsigned short* __restrict__ w3t,
                      const int* __restrict__ flagp){
  int g = blockIdx.x*256 + threadIdx.x;
  if (g >= 32*256) return;
  int bf = *flagp;
  int n = g>>8, k = g&255;
  w3t[n*256+k] = f2b(ld_in(w3, k*32+n, bf));
}

// ---------------- CSR build ----------------
__global__ void k_count(const int* __restrict__ ei, int* __restrict__ deg){
  int g = blockIdx.x*256 + threadIdx.x;
  if (g < Ee) atomicAdd(&deg[ei[Ee+g]], 1);
}
__global__ void __launch_bounds__(256) k_scan_blk(const int* __restrict__ deg,
                                                  int* __restrict__ offtmp,
                                                  int* __restrict__ bsum){
  __shared__ int s[256];
  int t = threadIdx.x, i = blockIdx.x*256 + t;
  int v = (i<Nn) ? deg[i]+1 : 0;
  s[t]=v; __syncthreads();
  #pragma unroll
  for (int d=1; d<256; d<<=1){
    int x = (t>=d)? s[t-d] : 0; __syncthreads();
    s[t]+=x; __syncthreads();
  }
  if (i<Nn) offtmp[i] = s[t]-v;
  if (t==255) bsum[blockIdx.x] = s[255];
}
__global__ void __launch_bounds__(256) k_scan_top(const int* __restrict__ bsum,
                                                  int* __restrict__ bpre,
                                                  int* __restrict__ off){
  __shared__ int s[256];
  int t=threadIdx.x;
  int v = (t<196)? bsum[t]:0;
  s[t]=v; __syncthreads();
  #pragma unroll
  for (int d=1;d<256;d<<=1){ int x=(t>=d)?s[t-d]:0; __syncthreads(); s[t]+=x; __syncthreads(); }
  if (t<196) bpre[t]=s[t]-v;
  if (t==0) off[Nn]=ET;
}
__global__ void __launch_bounds__(256) k_scan_add(const int* __restrict__ offtmp,
                                                  const int* __restrict__ bpre,
                                                  int* __restrict__ off,
                                                  int* __restrict__ cursor){
  int i = blockIdx.x*256 + threadIdx.x;
  if (i<Nn){ int st = offtmp[i]+bpre[i>>8]; off[i]=st; cursor[i]=st; }
}
__global__ void k_fill(const int* __restrict__ ei, int* __restrict__ cursor,
                       int* __restrict__ csr){
  int g = blockIdx.x*256 + threadIdx.x;
  if (g < Ee){
    int s = ei[g], d = ei[Ee+g];
    int p = atomicAdd(&cursor[d],1);
    csr[p] = s;
  } else if (g < ET){
    int n = g - Ee;
    int p = atomicAdd(&cursor[n],1);
    csr[p] = n;
  }
}

// ---------------- gemm1 (K=16, VALU f32 -> bf16 out) ----------------
__global__ void __launch_bounds__(256) k_gemm1(const float* __restrict__ xf,
                                               const float* __restrict__ W,
                                               unsigned short* __restrict__ out){
  __shared__ float Ws[DIN*F];
  __shared__ float xs[64*DIN];
  int row0 = blockIdx.x*64;
  for (int i=threadIdx.x;i<DIN*F;i+=256) Ws[i]=W[i];
  for (int i=threadIdx.x;i<64*DIN;i+=256){
    int row = row0 + (i>>4);
    xs[i] = (row<Nn) ? xf[(long)row*DIN + (i&15)] : 0.f;
  }
  __syncthreads();
  for (int r=0;r<64;r++){
    int row = row0 + r;
    if (row>=Nn) break;
    float a=0.f;
    #pragma unroll
    for (int k=0;k<DIN;k++) a += xs[r*DIN+k]*Ws[k*F+threadIdx.x];
    out[(long)row*F + threadIdx.x] = f2b(a);
  }
}

// ---------------- MFMA GEMM: C[M,N] = A[M,256] @ BT[N,256]^T, bf16 in/out ----------------
template<int BM,int BN,int WAVES_M,int WAVES_N>
__global__ void __launch_bounds__(256) k_gemm_mfma(const unsigned short* __restrict__ Ag,
                                                   const unsigned short* __restrict__ BTg,
                                                   unsigned short* __restrict__ Cg,
                                                   int M, int N, int nMB){
  constexpr int WMT = BM/(WAVES_M*16);
  constexpr int WNT = BN/(WAVES_N*16);
  __shared__ unsigned short As[4*BM*8];
  __shared__ unsigned short Bs[4*BN*8];
  int bm = blockIdx.x % nMB, bn = blockIdx.x / nMB;
  int row0 = bm*BM, col0 = bn*BN;
  int tid = threadIdx.x, lane = tid&63, wid = tid>>6;
  int wm = wid % WAVES_M, wn = wid / WAVES_M;
  f32x4 acc[WMT][WNT];
  #pragma unroll
  for (int m=0;m<WMT;m++)
    #pragma unroll
    for (int n=0;n<WNT;n++){ acc[m][n].x=0.f; acc[m][n].y=0.f; acc[m][n].z=0.f; acc[m][n].w=0.f; }

  int cl = lane>>4, rl = lane&15;
  for (int kk=0; kk<256; kk+=32){
    __syncthreads();
    for (int idx=tid; idx<4*BM; idx+=256){
      int r = idx>>2, c = idx&3;
      short8v v = *(const short8v*)(Ag + (size_t)(row0+r)*256 + kk + c*8);
      *(short8v*)(As + (c*BM + (r ^ (c<<2)))*8) = v;
    }
    for (int idx=tid; idx<4*BN; idx+=256){
      int r = idx>>2, c = idx&3;
      short8v v = *(const short8v*)(BTg + (size_t)(col0+r)*256 + kk + c*8);
      *(short8v*)(Bs + (c*BN + (r ^ (c<<2)))*8) = v;
    }
    __syncthreads();
    short8v af[WMT], bfv[WNT];
    #pragma unroll
    for (int m=0;m<WMT;m++){
      int r = wm*WMT*16 + m*16 + rl;
      af[m] = *(const short8v*)(As + (cl*BM + (r ^ (cl<<2)))*8);
    }
    #pragma unroll
    for (int n=0;n<WNT;n++){
      int r = wn*WNT*16 + n*16 + rl;
      bfv[n] = *(const short8v*)(Bs + (cl*BN + (r ^ (cl<<2)))*8);
    }
    #pragma unroll
    for (int m=0;m<WMT;m++)
      #pragma unroll
      for (int n=0;n<WNT;n++)
        acc[m][n] = __builtin_amdgcn_mfma_f32_16x16x32_bf16(af[m], bfv[n], acc[m][n], 0,0,0);
  }
  #pragma unroll
  for (int m=0;m<WMT;m++){
    int rbase = row0 + wm*WMT*16 + m*16 + (lane>>4)*4;
    #pragma unroll
    for (int n=0;n<WNT;n++){
      int col = col0 + wn*WNT*16 + n*16 + (lane&15);
      #pragma unroll
      for (int q=0;q<4;q++){
        int row = rbase + q;
        if (row < M) Cg[(size_t)row*N + col] = f2b(acc[m][n][q]);
      }
    }
  }
}

// ---------------- attention scores (bf16 h) ----------------
__global__ void __launch_bounds__(256) k_asad(const unsigned short* __restrict__ Hn,
                                              const float* __restrict__ asw,
                                              const float* __restrict__ adw,
                                              float* __restrict__ as4,
                                              float* __restrict__ ad4){
  int wid = threadIdx.x>>6, lane = threadIdx.x&63;
  int n = blockIdx.x*4 + wid;
  if (n>=Nn) return;
  #pragma unroll
  for (int h=0;h<4;h++){
    float v  = b2f(Hn[(long)n*F + h*64 + lane]);
    float ps = wsum64(v*asw[h*64+lane]);
    float pd = wsum64(v*adw[h*64+lane]);
    if (lane==0){ as4[n*4+h]=ps; ad4[n*4+h]=pd; }
  }
}

// ---------------- GAT aggregation (wave per dst node, bf16 gather) ----------------
__global__ void __launch_bounds__(256) k_agg(const unsigned short* __restrict__ Hs,
                                             const float* __restrict__ as4,
                                             const float* __restrict__ ad4,
                                             const float* __restrict__ bias,
                                             const int* __restrict__ off,
                                             const int* __restrict__ csr,
                                             unsigned short* __restrict__ out){
  int wid = threadIdx.x>>6, lane = threadIdx.x&63;
  int n = blockIdx.x*4 + wid;
  if (n>=Nn) return;
  int o0=off[n], o1=off[n+1];
  float ad0=ad4[n*4+0], ad1=ad4[n*4+1], ad2=ad4[n*4+2], ad3=ad4[n*4+3];
  float m0=-1e30f,m1=-1e30f,m2=-1e30f,m3=-1e30f;
  for (int e=o0+lane; e<o1; e+=64){
    const float4 sc = *reinterpret_cast<const float4*>(as4 + (size_t)csr[e]*4);
    float t0=sc.x+ad0; t0=t0>0.f?t0:0.2f*t0; m0=fmaxf(m0,t0);
    float t1=sc.y+ad1; t1=t1>0.f?t1:0.2f*t1; m1=fmaxf(m1,t1);
    float t2=sc.z+ad2; t2=t2>0.f?t2:0.2f*t2; m2=fmaxf(m2,t2);
    float t3=sc.w+ad3; t3=t3>0.f?t3:0.2f*t3; m3=fmaxf(m3,t3);
  }
  m0=wmax64(m0); m1=wmax64(m1); m2=wmax64(m2); m3=wmax64(m3);
  float s0=0,s1=0,s2=0,s3=0;
  for (int e=o0+lane; e<o1; e+=64){
    const float4 sc = *reinterpret_cast<const float4*>(as4 + (size_t)csr[e]*4);
    float t0=sc.x+ad0; t0=t0>0.f?t0:0.2f*t0; s0+=expf(t0-m0);
    float t1=sc.y+ad1; t1=t1>0.f?t1:0.2f*t1; s1+=expf(t1-m1);
    float t2=sc.z+ad2; t2=t2>0.f?t2:0.2f*t2; s2+=expf(t2-m2);
    float t3=sc.w+ad3; t3=t3>0.f?t3:0.2f*t3; s3+=expf(t3-m3);
  }
  s0=1.f/(wsum64(s0)+1e-16f); s1=1.f/(wsum64(s1)+1e-16f);
  s2=1.f/(wsum64(s2)+1e-16f); s3=1.f/(wsum64(s3)+1e-16f);
  int hh = lane>>4;
  float mxh = (hh&2) ? ((hh&1)?m3:m2) : ((hh&1)?m1:m0);
  float rdh = (hh&2) ? ((hh&1)?s3:s2) : ((hh&1)?s1:s0);
  float adh = (hh&2) ? ((hh&1)?ad3:ad2) : ((hh&1)?ad1:ad0);
  float a0=0,a1=0,a2=0,a3=0;
  for (int e=o0; e<o1; e++){
    int s=csr[e];
    const float4 sc = *reinterpret_cast<const float4*>(as4 + (size_t)s*4);
    float t = (hh&2)?((hh&1)?sc.w:sc.z):((hh&1)?sc.y:sc.x);
    t += adh; t = t>0.f?t:0.2f*t;
    float w = expf(t-mxh)*rdh;
    const ushort4 hv = *reinterpret_cast<const ushort4*>(Hs + (size_t)s*F + lane*4);
    a0 += w*b2f(hv.x); a1 += w*b2f(hv.y); a2 += w*b2f(hv.z); a3 += w*b2f(hv.w);
  }
  int c = lane*4;
  ushort4 ov;
  ov.x = f2b(a0 + bias[c  ]);
  ov.y = f2b(a1 + bias[c+1]);
  ov.z = f2b(a2 + bias[c+2]);
  ov.w = f2b(a3 + bias[c+3]);
  *reinterpret_cast<ushort4*>(out + (long)n*F + c) = ov;
}

// ---------------- LayerNorm + ELU (bf16 in/out) ----------------
__global__ void __launch_bounds__(256) k_lnelu(const unsigned short* __restrict__ in,
                                               const float* __restrict__ g,
                                               const float* __restrict__ be,
                                               unsigned short* __restrict__ out){
  int wid=threadIdx.x>>6, lane=threadIdx.x&63;
  int n = blockIdx.x*4 + wid;
  if (n>=Nn) return;
  const ushort4 uv = *reinterpret_cast<const ushort4*>(in + (long)n*F + lane*4);
  float vx=b2f(uv.x), vy=b2f(uv.y), vz=b2f(uv.z), vw=b2f(uv.w);
  float s = wsum64(vx+vy+vz+vw);
  float mu = s*(1.f/256.f);
  float dx=vx-mu, dy=vy-mu, dz=vz-mu, dw=vw-mu;
  float q = wsum64(dx*dx+dy*dy+dz*dz+dw*dw);
  float r = rsqrtf(q*(1.f/256.f) + 1e-5f);
  int c = lane*4;
  const float4 gv = *reinterpret_cast<const float4*>(g+c);
  const float4 bv = *reinterpret_cast<const float4*>(be+c);
  float y0=dx*r*gv.x+bv.x, y1=dy*r*gv.y+bv.y, y2=dz*r*gv.z+bv.z, y3=dw*r*gv.w+bv.w;
  y0 = y0>0.f?y0:expm1f(y0);
  y1 = y1>0.f?y1:expm1f(y1);
  y2 = y2>0.f?y2:expm1f(y2);
  y3 = y3>0.f?y3:expm1f(y3);
  ushort4 ov; ov.x=f2b(y0); ov.y=f2b(y1); ov.z=f2b(y2); ov.w=f2b(y3);
  *reinterpret_cast<ushort4*>(out + (long)n*F + c) = ov;
}

// ---------------- layer 3 scores + aggregation ----------------
__global__ void __launch_bounds__(256) k_asad3(const unsigned short* __restrict__ C3,
                                               const float* __restrict__ asw,
                                               const float* __restrict__ adw,
                                               float* __restrict__ s3,
                                               float* __restrict__ d3){
  int wid=threadIdx.x>>6, lane=threadIdx.x&63;
  int n = blockIdx.x*4 + wid;
  if (n>=Nn) return;
  float v = (lane<32) ? b2f(C3[(long)n*DO + lane]) : 0.f;
  float wa = (lane<32) ? asw[lane] : 0.f;
  float wd = (lane<32) ? adw[lane] : 0.f;
  float ps = wsum64(v*wa);
  float pd = wsum64(v*wd);
  if (lane==0){ s3[n]=ps; d3[n]=pd; }
}

__global__ void __launch_bounds__(256) k_agg3(const unsigned short* __restrict__ C3,
                                              const float* __restrict__ s3,
                                              const float* __restrict__ d3,
                                              const float* __restrict__ b3,
                                              const int* __restrict__ off,
                                              const int* __restrict__ csr,
                                              float* __restrict__ h3f,
                                              void* __restrict__ dout,
                                              const int* __restrict__ flagp){
  int wid=threadIdx.x>>6, lane=threadIdx.x&63;
  int n = blockIdx.x*4 + wid;
  if (n>=Nn) return;
  int bf = *flagp;
  int o0=off[n], o1=off[n+1];
  float adn = d3[n];
  float mx=-1e30f;
  for (int e=o0+lane;e<o1;e+=64){
    float t=s3[csr[e]]+adn; t=t>0.f?t:0.2f*t; mx=fmaxf(mx,t);
  }
  mx=wmax64(mx);
  float sm=0.f;
  for (int e=o0+lane;e<o1;e+=64){
    float t=s3[csr[e]]+adn; t=t>0.f?t:0.2f*t; sm+=expf(t-mx);
  }
  sm=wsum64(sm);
  float rd=1.f/(sm+1e-16f);
  int c=lane&31, half=lane>>5;
  float acc=0.f;
  for (int e0=o0;e0<o1;e0+=2){
    int e=e0+half;
    if (e<o1){
      int s=csr[e];
      float t=s3[s]+adn; t=t>0.f?t:0.2f*t;
      float w=expf(t-mx)*rd;
      acc += w*b2f(C3[(size_t)s*DO+c]);
    }
  }
  acc += __shfl_xor(acc,32);
  if (lane<32){
    float v = acc + b3[c];
    h3f[(long)n*DO+c] = v;
    st_out(dout, bf, (long)n*DO+c, v);
  }
}

// ---------------- risk head ----------------
__global__ void __launch_bounds__(256) k_risk(const float* __restrict__ h3f,
                                              const float* __restrict__ wf,
                                              void* __restrict__ dout,
                                              const int* __restrict__ flagp){
  int n = blockIdx.x*256 + threadIdx.x;
  if (n>=Nn) return;
  int bf = *flagp;
  float hv[32];
  #pragma unroll
  for (int k=0;k<32;k++) hv[k]=h3f[(long)n*32+k];
  float t1[32];
  #pragma unroll
  for (int j=0;j<32;j++){
    float s = wf[BR1O+j];
    #pragma unroll
    for (int k=0;k<32;k++) s += hv[k]*wf[WR1O+k*32+j];
    t1[j] = fmaxf(s,0.f);
  }
  #pragma unroll
  for (int o=0;o<6;o++){
    float s = wf[BR2O+o];
    #pragma unroll
    for (int j=0;j<32;j++) s += t1[j]*wf[WR2O+j*6+o];
    float r = 1.f/(1.f+expf(-s));
    st_out(dout, bf, (long)Nn*32 + (long)n*6 + o, r);
  }
}

// ---------------- launcher ----------------
extern "C" void kernel_launch(void* const* d_in, const int* in_sizes, int n_in,
                              void* d_out, int out_size, void* d_ws, size_t ws_size,
                              hipStream_t stream){
  char* base = (char*)d_ws;
  size_t cur = 0;
  auto alloc = [&](size_t bytes)->char*{
    cur = (cur + 255) & ~(size_t)255;
    char* r = base + cur; cur += bytes; return r;
  };
  int*   flag = (int*)  alloc(4);
  float* wf   = (float*)alloc(sizeof(float)*WTOT);
  float* xf   = (float*)alloc(sizeof(float)*(size_t)Nn*DIN);
  unsigned short* w2t = (unsigned short*)alloc(sizeof(short)*256*256);
  unsigned short* w3t = (unsigned short*)alloc(sizeof(short)*32*256);
  int*   deg  = (int*)  alloc(sizeof(int)*Nn);
  int*   offt = (int*)  alloc(sizeof(int)*Nn);
  int*   bsum = (int*)  alloc(sizeof(int)*256);
  int*   bpre = (int*)  alloc(sizeof(int)*256);
  int*   off  = (int*)  alloc(sizeof(int)*(Nn+1));
  int*   curs = (int*)  alloc(sizeof(int)*Nn);
  int*   csr  = (int*)  alloc(sizeof(int)*ET);
  unsigned short* P = (unsigned short*)alloc(sizeof(short)*(size_t)Np*F);
  unsigned short* Q = (unsigned short*)alloc(sizeof(short)*(size_t)Np*F);
  unsigned short* R = (unsigned short*)alloc(sizeof(short)*(size_t)Np*F);
  unsigned short* C3 = (unsigned short*)alloc(sizeof(short)*(size_t)Np*DO);
  float* as4  = (float*)alloc(sizeof(float)*(size_t)Nn*4);
  float* ad4  = (float*)alloc(sizeof(float)*(size_t)Nn*4);
  float* s3   = (float*)alloc(sizeof(float)*Nn);
  float* d3   = (float*)alloc(sizeof(float)*Nn);
  float* h3f  = (float*)alloc(sizeof(float)*(size_t)Nn*DO);

  const int* ei = (const int*)d_in[1];
  InPtrs ip;
  for (int i=0;i<22;i++) ip.p[i]=d_in[i];

  k_detect<<<1,256,0,stream>>>((const unsigned*)d_in[0], flag);
  {
    int total = Nn*DIN + WTOT;
    k_convert<<<(total+255)/256,256,0,stream>>>(ip, xf, wf, flag);
  }
  k_w2t<<<256,256,0,stream>>>(d_in[6], w2t, flag);
  k_w3t<<<32,256,0,stream>>>(d_in[10], w3t, flag);

  (void)hipMemsetAsync(deg, 0, sizeof(int)*Nn, stream);
  k_count<<<(Ee+255)/256,256,0,stream>>>(ei, deg);
  k_scan_blk<<<196,256,0,stream>>>(deg, offt, bsum);
  k_scan_top<<<1,256,0,stream>>>(bsum, bpre, off);
  k_scan_add<<<196,256,0,stream>>>(offt, bpre, off, curs);
  k_fill<<<(ET+255)/256,256,0,stream>>>(ei, curs, csr);

  dim3 wg((Nn+3)/4);
  constexpr int nMB = (Nn + 127)/128;   // 391
  // layer 1
  k_gemm1<<<(Nn+63)/64,256,0,stream>>>(xf, wf+W1O, P);
  k_asad <<<wg,256,0,stream>>>(P, wf+A1S, wf+A1D, as4, ad4);
  k_agg  <<<wg,256,0,stream>>>(P, as4, ad4, wf+B1O, off, csr, Q);
  k_lnelu<<<wg,256,0,stream>>>(Q, wf+G1O, wf+BE1O, R);
  // layer 2 (MFMA)
  k_gemm_mfma<128,128,2,2><<<nMB*2,256,0,stream>>>(R, w2t, P, Nn, 256, nMB);
  k_asad <<<wg,256,0,stream>>>(P, wf+A2S, wf+A2D, as4, ad4);
  k_agg  <<<wg,256,0,stream>>>(P, as4, ad4, wf+B2O, off, csr, Q);
  k_lnelu<<<wg,256,0,stream>>>(Q, wf+G2O, wf+BE2O, R);
  // layer 3 (MFMA, N=32)
  k_gemm_mfma<128,32,4,1><<<nMB,256,0,stream>>>(R, w3t, C3, Nn, 32, nMB);
  k_asad3<<<wg,256,0,stream>>>(C3, wf+A3S, wf+A3D, s3, d3);
  k_agg3 <<<wg,256,0,stream>>>(C3, s3, d3, wf+B3O, off, csr, h3f, d_out, flag);
  k_risk <<<(Nn+255)/256,256,0,stream>>>(h3f, wf, d_out, flag);
}

// Round 3
// 563.041 us; speedup vs baseline: 1.8980x; 1.3791x over previous
//
#include <hip/hip_runtime.h>
#include <hip/hip_bf16.h>
#include <cmath>

// ---------------- problem constants ----------------
constexpr int Nn  = 50000;
constexpr int Np  = 50176;       // Nn padded to 256 (MFMA tile tail reads)
constexpr int Ee  = 800000;
constexpr int ET  = Ee + Nn;     // edges + self loops
constexpr int F   = 256;         // H*C
constexpr int DIN = 16;
constexpr int DO  = 32;

// f32 weight block offsets
constexpr int W1O=0, A1S=4096, A1D=4352, B1O=4608,
              A2S=4864, A2D=5120, B2O=5376,
              A3S=5632, A3D=5664, B3O=5696,
              G1O=5728, BE1O=5984, G2O=6240, BE2O=6496,
              WR1O=6752, BR1O=7776, WR2O=7808, BR2O=8000, WTOT=8006;

struct InPtrs { const void* p[22]; };

typedef __attribute__((ext_vector_type(8))) short short8v;
typedef __attribute__((ext_vector_type(8))) unsigned short ushort8v;
typedef __attribute__((ext_vector_type(4))) float f32x4;

__device__ __forceinline__ float ld_in(const void* p, int i, int bf){
  if (bf){ unsigned u = (unsigned)((const unsigned short*)p)[i];
           union{unsigned u; float f;} c; c.u = u<<16; return c.f; }
  return ((const float*)p)[i];
}
__device__ __forceinline__ float b2f(unsigned short u){
  union{unsigned u; float f;} c; c.u = ((unsigned)u)<<16; return c.f;
}
__device__ __forceinline__ unsigned short f2b(float f){
  union{float f; unsigned u;} c; c.f=f; unsigned u=c.u;
  return (unsigned short)((u + 0x7fffu + ((u>>16)&1u))>>16);
}
__device__ __forceinline__ void st_out(void* o, int bf, long i, float v){
  if (bf) ((unsigned short*)o)[i] = f2b(v);
  else ((float*)o)[i]=v;
}
__device__ __forceinline__ float wmax64(float v){
  #pragma unroll
  for (int o=32;o;o>>=1) v = fmaxf(v, __shfl_xor(v,o));
  return v;
}
__device__ __forceinline__ float wsum64(float v){
  #pragma unroll
  for (int o=32;o;o>>=1) v += __shfl_xor(v,o);
  return v;
}

// ---------------- dtype detect ----------------
__global__ void k_detect(const unsigned* __restrict__ xr, int* __restrict__ flag){
  __shared__ int cnt;
  if (threadIdx.x==0) cnt=0;
  __syncthreads();
  int bad=0;
  for (int i=threadIdx.x;i<2048;i+=256){
    unsigned lo = xr[i]&0xffffu;
    unsigned ex = (lo>>7)&0xffu;
    if (ex>=133u) bad++;
  }
  atomicAdd(&cnt,bad);
  __syncthreads();
  if (threadIdx.x==0) *flag = (cnt<8) ? 1 : 0;   // 1 = inputs are bf16
}

// ---------------- convert inputs ----------------
__global__ void k_convert(InPtrs ip, float* __restrict__ xf, float* __restrict__ wf,
                          const int* __restrict__ flagp){
  int g = blockIdx.x*256 + threadIdx.x;
  int bf = *flagp;
  if (g < Nn*DIN){ xf[g] = ld_in(ip.p[0], g, bf); return; }
  int t = g - Nn*DIN;
  if (t >= WTOT) return;
  const int SIX[18]={2,3,4,5,7,8,9,11,12,13,14,15,16,17,18,19,20,21};
  const int SOF[18]={W1O,A1S,A1D,B1O,A2S,A2D,B2O,A3S,A3D,B3O,
                     G1O,BE1O,G2O,BE2O,WR1O,BR1O,WR2O,BR2O};
  const int SSZ[18]={4096,256,256,256,256,256,256,32,32,32,
                     256,256,256,256,1024,32,192,6};
  for (int j=0;j<18;j++){
    if (t < SSZ[j]){ wf[SOF[j]+t] = ld_in(ip.p[SIX[j]], t, bf); return; }
    t -= SSZ[j];
  }
}

// transpose W2 [256,256] -> W2T bf16 [N][K]
__global__ void k_w2t(const void* __restrict__ w2, unsigned short* __restrict__ w2t,
                      const int* __restrict__ flagp){
  int g = blockIdx.x*256 + threadIdx.x;
  if (g >= 256*256) return;
  int bf = *flagp;
  int n = g>>8, k = g&255;
  w2t[n*256+k] = f2b(ld_in(w2, k*256+n, bf));
}
// transpose W3 [256,32] -> W3T bf16 [32][256]
__global__ void k_w3t(const void* __restrict__ w3, unsigned short* __restrict__ w3t,
                      const int* __restrict__ flagp){
  int g = blockIdx.x*256 + threadIdx.x;
  if (g >= 32*256) return;
  int bf = *flagp;
  int n = g>>8, k = g&255;
  w3t[n*256+k] = f2b(ld_in(w3, k*32+n, bf));
}

// ---------------- CSR build ----------------
__global__ void k_count(const int* __restrict__ ei, int* __restrict__ deg){
  int g = blockIdx.x*256 + threadIdx.x;
  if (g < Ee) atomicAdd(&deg[ei[Ee+g]], 1);
}
__global__ void __launch_bounds__(256) k_scan_blk(const int* __restrict__ deg,
                                                  int* __restrict__ offtmp,
                                                  int* __restrict__ bsum){
  __shared__ int s[256];
  int t = threadIdx.x, i = blockIdx.x*256 + t;
  int v = (i<Nn) ? deg[i]+1 : 0;
  s[t]=v; __syncthreads();
  #pragma unroll
  for (int d=1; d<256; d<<=1){
    int x = (t>=d)? s[t-d] : 0; __syncthreads();
    s[t]+=x; __syncthreads();
  }
  if (i<Nn) offtmp[i] = s[t]-v;
  if (t==255) bsum[blockIdx.x] = s[255];
}
__global__ void __launch_bounds__(256) k_scan_top(const int* __restrict__ bsum,
                                                  int* __restrict__ bpre,
                                                  int* __restrict__ off){
  __shared__ int s[256];
  int t=threadIdx.x;
  int v = (t<196)? bsum[t]:0;
  s[t]=v; __syncthreads();
  #pragma unroll
  for (int d=1;d<256;d<<=1){ int x=(t>=d)?s[t-d]:0; __syncthreads(); s[t]+=x; __syncthreads(); }
  if (t<196) bpre[t]=s[t]-v;
  if (t==0) off[Nn]=ET;
}
__global__ void __launch_bounds__(256) k_scan_add(const int* __restrict__ offtmp,
                                                  const int* __restrict__ bpre,
                                                  int* __restrict__ off,
                                                  int* __restrict__ cursor){
  int i = blockIdx.x*256 + threadIdx.x;
  if (i<Nn){ int st = offtmp[i]+bpre[i>>8]; off[i]=st; cursor[i]=st; }
}
__global__ void k_fill(const int* __restrict__ ei, int* __restrict__ cursor,
                       int* __restrict__ csr){
  int g = blockIdx.x*256 + threadIdx.x;
  if (g < Ee){
    int s = ei[g], d = ei[Ee+g];
    int p = atomicAdd(&cursor[d],1);
    csr[p] = s;
  } else if (g < ET){
    int n = g - Ee;
    int p = atomicAdd(&cursor[n],1);
    csr[p] = n;
  }
}

// ---------------- gemm1 (K=16, VALU f32 -> bf16 out) ----------------
__global__ void __launch_bounds__(256) k_gemm1(const float* __restrict__ xf,
                                               const float* __restrict__ W,
                                               unsigned short* __restrict__ out){
  __shared__ float Ws[DIN*F];
  __shared__ float xs[64*DIN];
  int row0 = blockIdx.x*64;
  for (int i=threadIdx.x;i<DIN*F;i+=256) Ws[i]=W[i];
  for (int i=threadIdx.x;i<64*DIN;i+=256){
    int row = row0 + (i>>4);
    xs[i] = (row<Nn) ? xf[(long)row*DIN + (i&15)] : 0.f;
  }
  __syncthreads();
  for (int r=0;r<64;r++){
    int row = row0 + r;
    if (row>=Nn) break;
    float a=0.f;
    #pragma unroll
    for (int k=0;k<DIN;k++) a += xs[r*DIN+k]*Ws[k*F+threadIdx.x];
    out[(long)row*F + threadIdx.x] = f2b(a);
  }
}

// ---------------- MFMA GEMM: C[M,N] = A[M,256] @ BT[N,256]^T ----------------
template<int BM,int BN,int WAVES_M,int WAVES_N>
__global__ void __launch_bounds__(256) k_gemm_mfma(const unsigned short* __restrict__ Ag,
                                                   const unsigned short* __restrict__ BTg,
                                                   unsigned short* __restrict__ Cg,
                                                   int M, int N, int nMB){
  constexpr int WMT = BM/(WAVES_M*16);
  constexpr int WNT = BN/(WAVES_N*16);
  __shared__ unsigned short As[4*BM*8];
  __shared__ unsigned short Bs[4*BN*8];
  int bm = blockIdx.x % nMB, bn = blockIdx.x / nMB;
  int row0 = bm*BM, col0 = bn*BN;
  int tid = threadIdx.x, lane = tid&63, wid = tid>>6;
  int wm = wid % WAVES_M, wn = wid / WAVES_M;
  f32x4 acc[WMT][WNT];
  #pragma unroll
  for (int m=0;m<WMT;m++)
    #pragma unroll
    for (int n=0;n<WNT;n++){ acc[m][n].x=0.f; acc[m][n].y=0.f; acc[m][n].z=0.f; acc[m][n].w=0.f; }

  int cl = lane>>4, rl = lane&15;
  for (int kk=0; kk<256; kk+=32){
    __syncthreads();
    for (int idx=tid; idx<4*BM; idx+=256){
      int r = idx>>2, c = idx&3;
      short8v v = *(const short8v*)(Ag + (size_t)(row0+r)*256 + kk + c*8);
      *(short8v*)(As + (c*BM + (r ^ (c<<2)))*8) = v;
    }
    for (int idx=tid; idx<4*BN; idx+=256){
      int r = idx>>2, c = idx&3;
      short8v v = *(const short8v*)(BTg + (size_t)(col0+r)*256 + kk + c*8);
      *(short8v*)(Bs + (c*BN + (r ^ (c<<2)))*8) = v;
    }
    __syncthreads();
    short8v af[WMT], bfv[WNT];
    #pragma unroll
    for (int m=0;m<WMT;m++){
      int r = wm*WMT*16 + m*16 + rl;
      af[m] = *(const short8v*)(As + (cl*BM + (r ^ (cl<<2)))*8);
    }
    #pragma unroll
    for (int n=0;n<WNT;n++){
      int r = wn*WNT*16 + n*16 + rl;
      bfv[n] = *(const short8v*)(Bs + (cl*BN + (r ^ (cl<<2)))*8);
    }
    #pragma unroll
    for (int m=0;m<WMT;m++)
      #pragma unroll
      for (int n=0;n<WNT;n++)
        acc[m][n] = __builtin_amdgcn_mfma_f32_16x16x32_bf16(af[m], bfv[n], acc[m][n], 0,0,0);
  }
  #pragma unroll
  for (int m=0;m<WMT;m++){
    int rbase = row0 + wm*WMT*16 + m*16 + (lane>>4)*4;
    #pragma unroll
    for (int n=0;n<WNT;n++){
      int col = col0 + wn*WNT*16 + n*16 + (lane&15);
      #pragma unroll
      for (int q=0;q<4;q++){
        int row = rbase + q;
        if (row < M) Cg[(size_t)row*N + col] = f2b(acc[m][n][q]);
      }
    }
  }
}

// ---------------- attention scores per node ----------------
__global__ void __launch_bounds__(256) k_asad(const unsigned short* __restrict__ Hn,
                                              const float* __restrict__ asw,
                                              const float* __restrict__ adw,
                                              float* __restrict__ as4,
                                              float* __restrict__ ad4){
  int wid = threadIdx.x>>6, lane = threadIdx.x&63;
  int n = blockIdx.x*4 + wid;
  if (n>=Nn) return;
  #pragma unroll
  for (int h=0;h<4;h++){
    float v  = b2f(Hn[(long)n*F + h*64 + lane]);
    float ps = wsum64(v*asw[h*64+lane]);
    float pd = wsum64(v*adw[h*64+lane]);
    if (lane==0){ as4[n*4+h]=ps; ad4[n*4+h]=pd; }
  }
}

// ---------------- per-node max+sum, writes unnormalized alpha (4 planes) ----------------
__global__ void __launch_bounds__(256) k_maxsum(const float* __restrict__ as4,
                                                const float* __restrict__ ad4,
                                                const int* __restrict__ off,
                                                const int* __restrict__ csr,
                                                float* __restrict__ alp,  // [4][ET]
                                                float* __restrict__ rd4){
  int wid = threadIdx.x>>6, lane = threadIdx.x&63;
  int n = blockIdx.x*4 + wid;
  if (n>=Nn) return;
  int o0=off[n], o1=off[n+1];
  const float4 adv = *reinterpret_cast<const float4*>(ad4 + (size_t)n*4);
  float m0=-1e30f,m1=-1e30f,m2=-1e30f,m3=-1e30f;
  for (int e=o0+lane; e<o1; e+=64){
    const float4 sc = *reinterpret_cast<const float4*>(as4 + (size_t)csr[e]*4);
    float t0=sc.x+adv.x; t0=t0>0.f?t0:0.2f*t0; m0=fmaxf(m0,t0);
    float t1=sc.y+adv.y; t1=t1>0.f?t1:0.2f*t1; m1=fmaxf(m1,t1);
    float t2=sc.z+adv.z; t2=t2>0.f?t2:0.2f*t2; m2=fmaxf(m2,t2);
    float t3=sc.w+adv.w; t3=t3>0.f?t3:0.2f*t3; m3=fmaxf(m3,t3);
  }
  m0=wmax64(m0); m1=wmax64(m1); m2=wmax64(m2); m3=wmax64(m3);
  float s0=0,s1=0,s2=0,s3=0;
  for (int e=o0+lane; e<o1; e+=64){
    const float4 sc = *reinterpret_cast<const float4*>(as4 + (size_t)csr[e]*4);
    float t0=sc.x+adv.x; t0=t0>0.f?t0:0.2f*t0; float e0=__expf(t0-m0);
    float t1=sc.y+adv.y; t1=t1>0.f?t1:0.2f*t1; float e1=__expf(t1-m1);
    float t2=sc.z+adv.z; t2=t2>0.f?t2:0.2f*t2; float e2=__expf(t2-m2);
    float t3=sc.w+adv.w; t3=t3>0.f?t3:0.2f*t3; float e3=__expf(t3-m3);
    alp[e]        = e0;
    alp[ET+e]     = e1;
    alp[2*ET+e]   = e2;
    alp[3*ET+e]   = e3;
    s0+=e0; s1+=e1; s2+=e2; s3+=e3;
  }
  s0=wsum64(s0); s1=wsum64(s1); s2=wsum64(s2); s3=wsum64(s3);
  if (lane==0){
    float4 r; r.x=1.f/(s0+1e-16f); r.y=1.f/(s1+1e-16f);
    r.z=1.f/(s2+1e-16f); r.w=1.f/(s3+1e-16f);
    *reinterpret_cast<float4*>(rd4 + (size_t)n*4) = r;
  }
}

// ---------------- GAT aggregation + bias + LayerNorm + ELU (layers 1,2) ----------------
__global__ void __launch_bounds__(256) k_agg(const unsigned short* __restrict__ Hs,
                                             const float* __restrict__ alp,
                                             const float* __restrict__ rd4,
                                             const float* __restrict__ bias,
                                             const float* __restrict__ gam,
                                             const float* __restrict__ bet,
                                             const int* __restrict__ off,
                                             const int* __restrict__ csr,
                                             unsigned short* __restrict__ out){
  int wid = threadIdx.x>>6, lane = threadIdx.x&63;
  int n = blockIdx.x*4 + wid;
  if (n>=Nn) return;
  int half = lane>>5, c8 = lane&31;       // channels c8*8 .. c8*8+7
  int h = c8>>3;
  const float* alph = alp + (size_t)h*ET;
  float rdh = rd4[(size_t)n*4 + h];
  int o0=off[n], o1=off[n+1];
  float a0=0,a1=0,a2=0,a3=0,a4=0,a5=0,a6=0,a7=0;
  int e = o0 + half;
  // 2 edges/iter (one per half-wave), unrolled x2 (4 edges in flight)
  for (; e+2 < o1; e += 4){
    int s0v=csr[e], s1v=csr[e+2];
    float w0 = alph[e]*rdh, w1 = alph[e+2]*rdh;
    const ushort8v hv0 = *reinterpret_cast<const ushort8v*>(Hs + (size_t)s0v*F + c8*8);
    const ushort8v hv1 = *reinterpret_cast<const ushort8v*>(Hs + (size_t)s1v*F + c8*8);
    a0 += w0*b2f(hv0[0]) + w1*b2f(hv1[0]);
    a1 += w0*b2f(hv0[1]) + w1*b2f(hv1[1]);
    a2 += w0*b2f(hv0[2]) + w1*b2f(hv1[2]);
    a3 += w0*b2f(hv0[3]) + w1*b2f(hv1[3]);
    a4 += w0*b2f(hv0[4]) + w1*b2f(hv1[4]);
    a5 += w0*b2f(hv0[5]) + w1*b2f(hv1[5]);
    a6 += w0*b2f(hv0[6]) + w1*b2f(hv1[6]);
    a7 += w0*b2f(hv0[7]) + w1*b2f(hv1[7]);
  }
  for (; e < o1; e += 2){
    int sv=csr[e];
    float w = alph[e]*rdh;
    const ushort8v hv = *reinterpret_cast<const ushort8v*>(Hs + (size_t)sv*F + c8*8);
    a0 += w*b2f(hv[0]); a1 += w*b2f(hv[1]); a2 += w*b2f(hv[2]); a3 += w*b2f(hv[3]);
    a4 += w*b2f(hv[4]); a5 += w*b2f(hv[5]); a6 += w*b2f(hv[6]); a7 += w*b2f(hv[7]);
  }
  // combine half-waves
  a0 += __shfl_xor(a0,32); a1 += __shfl_xor(a1,32);
  a2 += __shfl_xor(a2,32); a3 += __shfl_xor(a3,32);
  a4 += __shfl_xor(a4,32); a5 += __shfl_xor(a5,32);
  a6 += __shfl_xor(a6,32); a7 += __shfl_xor(a7,32);
  // bias
  int c = c8*8;
  const float4 bv0 = *reinterpret_cast<const float4*>(bias + c);
  const float4 bv1 = *reinterpret_cast<const float4*>(bias + c + 4);
  a0+=bv0.x; a1+=bv0.y; a2+=bv0.z; a3+=bv0.w;
  a4+=bv1.x; a5+=bv1.y; a6+=bv1.z; a7+=bv1.w;
  // LayerNorm over 256 (values duplicated across halves -> /512)
  float sl = a0+a1+a2+a3+a4+a5+a6+a7;
  float mu = wsum64(sl)*(1.f/512.f);
  float d0=a0-mu,d1=a1-mu,d2=a2-mu,d3=a3-mu,d4=a4-mu,d5=a5-mu,d6=a6-mu,d7=a7-mu;
  float ql = d0*d0+d1*d1+d2*d2+d3*d3+d4*d4+d5*d5+d6*d6+d7*d7;
  float var = wsum64(ql)*(1.f/512.f);
  float r = rsqrtf(var + 1e-5f);
  const float4 gv0 = *reinterpret_cast<const float4*>(gam + c);
  const float4 gv1 = *reinterpret_cast<const float4*>(gam + c + 4);
  const float4 ev0 = *reinterpret_cast<const float4*>(bet + c);
  const float4 ev1 = *reinterpret_cast<const float4*>(bet + c + 4);
  float y0=d0*r*gv0.x+ev0.x, y1=d1*r*gv0.y+ev0.y, y2=d2*r*gv0.z+ev0.z, y3=d3*r*gv0.w+ev0.w;
  float y4=d4*r*gv1.x+ev1.x, y5=d5*r*gv1.y+ev1.y, y6=d6*r*gv1.z+ev1.z, y7=d7*r*gv1.w+ev1.w;
  y0=y0>0.f?y0:expm1f(y0); y1=y1>0.f?y1:expm1f(y1);
  y2=y2>0.f?y2:expm1f(y2); y3=y3>0.f?y3:expm1f(y3);
  y4=y4>0.f?y4:expm1f(y4); y5=y5>0.f?y5:expm1f(y5);
  y6=y6>0.f?y6:expm1f(y6); y7=y7>0.f?y7:expm1f(y7);
  if (half==0){
    ushort8v ov;
    ov[0]=f2b(y0); ov[1]=f2b(y1); ov[2]=f2b(y2); ov[3]=f2b(y3);
    ov[4]=f2b(y4); ov[5]=f2b(y5); ov[6]=f2b(y6); ov[7]=f2b(y7);
    *reinterpret_cast<ushort8v*>(out + (size_t)n*F + c) = ov;
  }
}

// ---------------- layer 3 scores ----------------
__global__ void __launch_bounds__(256) k_asad3(const unsigned short* __restrict__ C3,
                                               const float* __restrict__ asw,
                                               const float* __restrict__ adw,
                                               float* __restrict__ s3,
                                               float* __restrict__ d3){
  int wid=threadIdx.x>>6, lane=threadIdx.x&63;
  int n = blockIdx.x*4 + wid;
  if (n>=Nn) return;
  float v = (lane<32) ? b2f(C3[(long)n*DO + lane]) : 0.f;
  float wa = (lane<32) ? asw[lane] : 0.f;
  float wd = (lane<32) ? adw[lane] : 0.f;
  float ps = wsum64(v*wa);
  float pd = wsum64(v*wd);
  if (lane==0){ s3[n]=ps; d3[n]=pd; }
}

__global__ void __launch_bounds__(256) k_maxsum3(const float* __restrict__ s3,
                                                 const float* __restrict__ d3,
                                                 const int* __restrict__ off,
                                                 const int* __restrict__ csr,
                                                 float* __restrict__ alp3,
                                                 float* __restrict__ rd3){
  int wid=threadIdx.x>>6, lane=threadIdx.x&63;
  int n = blockIdx.x*4 + wid;
  if (n>=Nn) return;
  int o0=off[n], o1=off[n+1];
  float dn = d3[n];
  float mx=-1e30f;
  for (int e=o0+lane;e<o1;e+=64){
    float t=s3[csr[e]]+dn; t=t>0.f?t:0.2f*t; mx=fmaxf(mx,t);
  }
  mx=wmax64(mx);
  float sm=0.f;
  for (int e=o0+lane;e<o1;e+=64){
    float t=s3[csr[e]]+dn; t=t>0.f?t:0.2f*t;
    float ev=__expf(t-mx);
    alp3[e]=ev; sm+=ev;
  }
  sm=wsum64(sm);
  if (lane==0) rd3[n]=1.f/(sm+1e-16f);
}

// ---------------- layer 3 aggregation (8 lanes/edge) ----------------
__global__ void __launch_bounds__(256) k_agg3(const unsigned short* __restrict__ C3,
                                              const float* __restrict__ alp3,
                                              const float* __restrict__ rd3,
                                              const float* __restrict__ b3,
                                              const int* __restrict__ off,
                                              const int* __restrict__ csr,
                                              float* __restrict__ h3f,
                                              void* __restrict__ dout,
                                              const int* __restrict__ flagp){
  int wid=threadIdx.x>>6, lane=threadIdx.x&63;
  int n = blockIdx.x*4 + wid;
  if (n>=Nn) return;
  int bf = *flagp;
  int grp = lane>>3, j = lane&7;          // 8 groups x 8 lanes; channels j*4..j*4+3
  float rd = rd3[n];
  int o0=off[n], o1=off[n+1];
  float a0=0,a1=0,a2=0,a3=0;
  for (int e=o0+grp; e<o1; e+=8){
    int s=csr[e];
    float w = alp3[e]*rd;
    const ushort4 hv = *reinterpret_cast<const ushort4*>(C3 + (size_t)s*DO + j*4);
    a0 += w*b2f(hv.x); a1 += w*b2f(hv.y); a2 += w*b2f(hv.z); a3 += w*b2f(hv.w);
  }
  #pragma unroll
  for (int o=8;o<64;o<<=1){
    a0 += __shfl_xor(a0,o); a1 += __shfl_xor(a1,o);
    a2 += __shfl_xor(a2,o); a3 += __shfl_xor(a3,o);
  }
  if (lane<8){
    int c = lane*4;
    const float4 bv = *reinterpret_cast<const float4*>(b3 + c);
    float v0=a0+bv.x, v1=a1+bv.y, v2=a2+bv.z, v3=a3+bv.w;
    float4 o4; o4.x=v0; o4.y=v1; o4.z=v2; o4.w=v3;
    *reinterpret_cast<float4*>(h3f + (size_t)n*DO + c) = o4;
    long bo = (long)n*DO + c;
    st_out(dout, bf, bo  , v0);
    st_out(dout, bf, bo+1, v1);
    st_out(dout, bf, bo+2, v2);
    st_out(dout, bf, bo+3, v3);
  }
}

// ---------------- risk head ----------------
__global__ void __launch_bounds__(256) k_risk(const float* __restrict__ h3f,
                                              const float* __restrict__ wf,
                                              void* __restrict__ dout,
                                              const int* __restrict__ flagp){
  int n = blockIdx.x*256 + threadIdx.x;
  if (n>=Nn) return;
  int bf = *flagp;
  float hv[32];
  #pragma unroll
  for (int k=0;k<32;k++) hv[k]=h3f[(long)n*32+k];
  float t1[32];
  #pragma unroll
  for (int j=0;j<32;j++){
    float s = wf[BR1O+j];
    #pragma unroll
    for (int k=0;k<32;k++) s += hv[k]*wf[WR1O+k*32+j];
    t1[j] = fmaxf(s,0.f);
  }
  #pragma unroll
  for (int o=0;o<6;o++){
    float s = wf[BR2O+o];
    #pragma unroll
    for (int j=0;j<32;j++) s += t1[j]*wf[WR2O+j*6+o];
    float r = 1.f/(1.f+expf(-s));
    st_out(dout, bf, (long)Nn*32 + (long)n*6 + o, r);
  }
}

// ---------------- launcher ----------------
extern "C" void kernel_launch(void* const* d_in, const int* in_sizes, int n_in,
                              void* d_out, int out_size, void* d_ws, size_t ws_size,
                              hipStream_t stream){
  char* base = (char*)d_ws;
  size_t cur = 0;
  auto alloc = [&](size_t bytes)->char*{
    cur = (cur + 255) & ~(size_t)255;
    char* r = base + cur; cur += bytes; return r;
  };
  int*   flag = (int*)  alloc(4);
  float* wf   = (float*)alloc(sizeof(float)*WTOT);
  float* xf   = (float*)alloc(sizeof(float)*(size_t)Nn*DIN);
  unsigned short* w2t = (unsigned short*)alloc(sizeof(short)*256*256);
  unsigned short* w3t = (unsigned short*)alloc(sizeof(short)*32*256);
  int*   deg  = (int*)  alloc(sizeof(int)*Nn);
  int*   offt = (int*)  alloc(sizeof(int)*Nn);
  int*   bsum = (int*)  alloc(sizeof(int)*256);
  int*   bpre = (int*)  alloc(sizeof(int)*256);
  int*   off  = (int*)  alloc(sizeof(int)*(Nn+1));
  int*   curs = (int*)  alloc(sizeof(int)*Nn);
  int*   csr  = (int*)  alloc(sizeof(int)*ET);
  unsigned short* G  = (unsigned short*)alloc(sizeof(short)*(size_t)Np*F);
  unsigned short* Hb = (unsigned short*)alloc(sizeof(short)*(size_t)Np*F);
  unsigned short* C3 = (unsigned short*)alloc(sizeof(short)*(size_t)Np*DO);
  float* as4  = (float*)alloc(sizeof(float)*(size_t)Nn*4);
  float* ad4  = (float*)alloc(sizeof(float)*(size_t)Nn*4);
  float* alp  = (float*)alloc(sizeof(float)*(size_t)4*ET);
  float* rd4  = (float*)alloc(sizeof(float)*(size_t)Nn*4);
  float* s3   = (float*)alloc(sizeof(float)*Nn);
  float* d3   = (float*)alloc(sizeof(float)*Nn);
  float* alp3 = (float*)alloc(sizeof(float)*(size_t)ET);
  float* rd3  = (float*)alloc(sizeof(float)*Nn);
  float* h3f  = (float*)alloc(sizeof(float)*(size_t)Nn*DO);

  const int* ei = (const int*)d_in[1];
  InPtrs ip;
  for (int i=0;i<22;i++) ip.p[i]=d_in[i];

  k_detect<<<1,256,0,stream>>>((const unsigned*)d_in[0], flag);
  {
    int total = Nn*DIN + WTOT;
    k_convert<<<(total+255)/256,256,0,stream>>>(ip, xf, wf, flag);
  }
  k_w2t<<<256,256,0,stream>>>(d_in[6], w2t, flag);
  k_w3t<<<32,256,0,stream>>>(d_in[10], w3t, flag);

  (void)hipMemsetAsync(deg, 0, sizeof(int)*Nn, stream);
  k_count<<<(Ee+255)/256,256,0,stream>>>(ei, deg);
  k_scan_blk<<<196,256,0,stream>>>(deg, offt, bsum);
  k_scan_top<<<1,256,0,stream>>>(bsum, bpre, off);
  k_scan_add<<<196,256,0,stream>>>(offt, bpre, off, curs);
  k_fill<<<(ET+255)/256,256,0,stream>>>(ei, curs, csr);

  dim3 wg((Nn+3)/4);
  constexpr int nMB = (Nn + 127)/128;   // 391
  // layer 1
  k_gemm1<<<(Nn+63)/64,256,0,stream>>>(xf, wf+W1O, G);
  k_asad  <<<wg,256,0,stream>>>(G, wf+A1S, wf+A1D, as4, ad4);
  k_maxsum<<<wg,256,0,stream>>>(as4, ad4, off, csr, alp, rd4);
  k_agg   <<<wg,256,0,stream>>>(G, alp, rd4, wf+B1O, wf+G1O, wf+BE1O, off, csr, Hb);
  // layer 2
  k_gemm_mfma<128,128,2,2><<<nMB*2,256,0,stream>>>(Hb, w2t, G, Nn, 256, nMB);
  k_asad  <<<wg,256,0,stream>>>(G, wf+A2S, wf+A2D, as4, ad4);
  k_maxsum<<<wg,256,0,stream>>>(as4, ad4, off, csr, alp, rd4);
  k_agg   <<<wg,256,0,stream>>>(G, alp, rd4, wf+B2O, wf+G2O, wf+BE2O, off, csr, Hb);
  // layer 3
  k_gemm_mfma<128,32,4,1><<<nMB,256,0,stream>>>(Hb, w3t, C3, Nn, 32, nMB);
  k_asad3 <<<wg,256,0,stream>>>(C3, wf+A3S, wf+A3D, s3, d3);
  k_maxsum3<<<wg,256,0,stream>>>(s3, d3, off, csr, alp3, rd3);
  k_agg3  <<<wg,256,0,stream>>>(C3, alp3, rd3, wf+B3O, off, csr, h3f, d_out, flag);
  k_risk  <<<(Nn+255)/256,256,0,stream>>>(h3f, wf, d_out, flag);
}

// Round 4
// 449.715 us; speedup vs baseline: 2.3762x; 1.2520x over previous
//
#include <hip/hip_runtime.h>
#include <hip/hip_bf16.h>
#include <cmath>

// ---------------- problem constants ----------------
constexpr int Nn  = 50000;
constexpr int Np  = 50176;       // Nn padded to 256
constexpr int Ee  = 800000;
constexpr int ET  = Ee + Nn;     // edges + self loops
constexpr int F   = 256;         // H*C
constexpr int DIN = 16;
constexpr int DO  = 32;

// f32 weight block offsets (W1 region unused; W1/W2/W3 live as bf16 transposed)
constexpr int W1O=0, A1S=4096, A1D=4352, B1O=4608,
              A2S=4864, A2D=5120, B2O=5376,
              A3S=5632, A3D=5664, B3O=5696,
              G1O=5728, BE1O=5984, G2O=6240, BE2O=6496,
              WR1O=6752, BR1O=7776, WR2O=7808, BR2O=8000, WTOT=8006;

struct InPtrs { const void* p[22]; };

typedef __attribute__((ext_vector_type(8))) short short8v;
typedef __attribute__((ext_vector_type(8))) unsigned short ushort8v;
typedef __attribute__((ext_vector_type(4))) float f32x4;

__device__ __forceinline__ float ld_in(const void* p, int i, int bf){
  if (bf){ unsigned u = (unsigned)((const unsigned short*)p)[i];
           union{unsigned u; float f;} c; c.u = u<<16; return c.f; }
  return ((const float*)p)[i];
}
__device__ __forceinline__ float b2f(unsigned short u){
  union{unsigned u; float f;} c; c.u = ((unsigned)u)<<16; return c.f;
}
__device__ __forceinline__ unsigned short f2b(float f){
  union{float f; unsigned u;} c; c.f=f; unsigned u=c.u;
  return (unsigned short)((u + 0x7fffu + ((u>>16)&1u))>>16);
}
__device__ __forceinline__ void st_out(void* o, int bf, long i, float v){
  if (bf) ((unsigned short*)o)[i] = f2b(v);
  else ((float*)o)[i]=v;
}
__device__ __forceinline__ float wsum64(float v){
  #pragma unroll
  for (int o=32;o;o>>=1) v += __shfl_xor(v,o);
  return v;
}

// ---------------- dtype detect ----------------
__global__ void k_detect(const unsigned* __restrict__ xr, int* __restrict__ flag){
  __shared__ int cnt;
  if (threadIdx.x==0) cnt=0;
  __syncthreads();
  int bad=0;
  for (int i=threadIdx.x;i<2048;i+=256){
    unsigned lo = xr[i]&0xffffu;
    unsigned ex = (lo>>7)&0xffu;
    if (ex>=133u) bad++;
  }
  atomicAdd(&cnt,bad);
  __syncthreads();
  if (threadIdx.x==0) *flag = (cnt<8) ? 1 : 0;   // 1 = inputs are bf16
}

// ---------------- convert small weights to f32 scratch ----------------
__global__ void k_convert(InPtrs ip, float* __restrict__ wf,
                          const int* __restrict__ flagp){
  int t = blockIdx.x*256 + threadIdx.x;
  int bf = *flagp;
  const int SIX[17]={3,4,5,7,8,9,11,12,13,14,15,16,17,18,19,20,21};
  const int SOF[17]={A1S,A1D,B1O,A2S,A2D,B2O,A3S,A3D,B3O,
                     G1O,BE1O,G2O,BE2O,WR1O,BR1O,WR2O,BR2O};
  const int SSZ[17]={256,256,256,256,256,256,32,32,32,
                     256,256,256,256,1024,32,192,6};
  for (int j=0;j<17;j++){
    if (t < SSZ[j]){ wf[SOF[j]+t] = ld_in(ip.p[SIX[j]], t, bf); return; }
    t -= SSZ[j];
  }
}

// x [Nn][16] -> xpad bf16 [Np][32] zero-padded
__global__ void k_xpad(const void* __restrict__ x, unsigned short* __restrict__ xp,
                       const int* __restrict__ flagp){
  int g = blockIdx.x*256 + threadIdx.x;
  if (g >= Np*32) return;
  int bf = *flagp;
  int row = g>>5, k = g&31;
  float v = (row<Nn && k<16) ? ld_in(x, row*16+k, bf) : 0.f;
  xp[g] = f2b(v);
}
// W1 [16][256] -> W1T bf16 [256][32] zero-padded
__global__ void k_w1t(const void* __restrict__ w1, unsigned short* __restrict__ w1t,
                      const int* __restrict__ flagp){
  int g = blockIdx.x*256 + threadIdx.x;
  if (g >= 256*32) return;
  int bf = *flagp;
  int n = g>>5, k = g&31;
  w1t[g] = (k<16) ? f2b(ld_in(w1, k*256+n, bf)) : (unsigned short)0;
}
// W2 [256,256] -> W2T bf16 [N][K]
__global__ void k_w2t(const void* __restrict__ w2, unsigned short* __restrict__ w2t,
                      const int* __restrict__ flagp){
  int g = blockIdx.x*256 + threadIdx.x;
  if (g >= 256*256) return;
  int bf = *flagp;
  int n = g>>8, k = g&255;
  w2t[n*256+k] = f2b(ld_in(w2, k*256+n, bf));
}
// W3 [256,32] -> W3T bf16 [32][256]
__global__ void k_w3t(const void* __restrict__ w3, unsigned short* __restrict__ w3t,
                      const int* __restrict__ flagp){
  int g = blockIdx.x*256 + threadIdx.x;
  if (g >= 32*256) return;
  int bf = *flagp;
  int n = g>>8, k = g&255;
  w3t[n*256+k] = f2b(ld_in(w3, k*32+n, bf));
}

// ---------------- CSR build ----------------
__global__ void k_count(const int* __restrict__ ei, int* __restrict__ deg){
  int g = blockIdx.x*256 + threadIdx.x;
  if (g < Ee) atomicAdd(&deg[ei[Ee+g]], 1);
}
__global__ void __launch_bounds__(256) k_scan_blk(const int* __restrict__ deg,
                                                  int* __restrict__ offtmp,
                                                  int* __restrict__ bsum){
  __shared__ int s[256];
  int t = threadIdx.x, i = blockIdx.x*256 + t;
  int v = (i<Nn) ? deg[i]+1 : 0;
  s[t]=v; __syncthreads();
  #pragma unroll
  for (int d=1; d<256; d<<=1){
    int x = (t>=d)? s[t-d] : 0; __syncthreads();
    s[t]+=x; __syncthreads();
  }
  if (i<Nn) offtmp[i] = s[t]-v;
  if (t==255) bsum[blockIdx.x] = s[255];
}
__global__ void __launch_bounds__(256) k_scan_top(const int* __restrict__ bsum,
                                                  int* __restrict__ bpre,
                                                  int* __restrict__ off){
  __shared__ int s[256];
  int t=threadIdx.x;
  int v = (t<196)? bsum[t]:0;
  s[t]=v; __syncthreads();
  #pragma unroll
  for (int d=1;d<256;d<<=1){ int x=(t>=d)?s[t-d]:0; __syncthreads(); s[t]+=x; __syncthreads(); }
  if (t<196) bpre[t]=s[t]-v;
  if (t==0) off[Nn]=ET;
}
__global__ void __launch_bounds__(256) k_scan_add(const int* __restrict__ offtmp,
                                                  const int* __restrict__ bpre,
                                                  int* __restrict__ off,
                                                  int* __restrict__ cursor){
  int i = blockIdx.x*256 + threadIdx.x;
  if (i<Nn){ int st = offtmp[i]+bpre[i>>8]; off[i]=st; cursor[i]=st; }
}
__global__ void k_fill(const int* __restrict__ ei, int* __restrict__ cursor,
                       int* __restrict__ csr){
  int g = blockIdx.x*256 + threadIdx.x;
  if (g < Ee){
    int s = ei[g], d = ei[Ee+g];
    int p = atomicAdd(&cursor[d],1);
    csr[p] = s;
  } else if (g < ET){
    int n = g - Ee;
    int p = atomicAdd(&cursor[n],1);
    csr[p] = n;
  }
}

// ---------------- MFMA GEMM: C[M,N] = A[M,KT] @ BT[N,KT]^T ----------------
template<int BM,int BN,int WAVES_M,int WAVES_N,int KT>
__global__ void __launch_bounds__(256) k_gemm_mfma(const unsigned short* __restrict__ Ag,
                                                   const unsigned short* __restrict__ BTg,
                                                   unsigned short* __restrict__ Cg,
                                                   int M, int N, int nMB){
  constexpr int WMT = BM/(WAVES_M*16);
  constexpr int WNT = BN/(WAVES_N*16);
  __shared__ unsigned short As[4*BM*8];
  __shared__ unsigned short Bs[4*BN*8];
  int bm = blockIdx.x % nMB, bn = blockIdx.x / nMB;
  int row0 = bm*BM, col0 = bn*BN;
  int tid = threadIdx.x, lane = tid&63, wid = tid>>6;
  int wm = wid % WAVES_M, wn = wid / WAVES_M;
  f32x4 acc[WMT][WNT];
  #pragma unroll
  for (int m=0;m<WMT;m++)
    #pragma unroll
    for (int n=0;n<WNT;n++){ acc[m][n].x=0.f; acc[m][n].y=0.f; acc[m][n].z=0.f; acc[m][n].w=0.f; }

  int cl = lane>>4, rl = lane&15;
  for (int kk=0; kk<KT; kk+=32){
    __syncthreads();
    for (int idx=tid; idx<4*BM; idx+=256){
      int r = idx>>2, c = idx&3;
      short8v v = *(const short8v*)(Ag + (size_t)(row0+r)*KT + kk + c*8);
      *(short8v*)(As + (c*BM + (r ^ (c<<2)))*8) = v;
    }
    for (int idx=tid; idx<4*BN; idx+=256){
      int r = idx>>2, c = idx&3;
      short8v v = *(const short8v*)(BTg + (size_t)(col0+r)*KT + kk + c*8);
      *(short8v*)(Bs + (c*BN + (r ^ (c<<2)))*8) = v;
    }
    __syncthreads();
    short8v af[WMT], bfv[WNT];
    #pragma unroll
    for (int m=0;m<WMT;m++){
      int r = wm*WMT*16 + m*16 + rl;
      af[m] = *(const short8v*)(As + (cl*BM + (r ^ (cl<<2)))*8);
    }
    #pragma unroll
    for (int n=0;n<WNT;n++){
      int r = wn*WNT*16 + n*16 + rl;
      bfv[n] = *(const short8v*)(Bs + (cl*BN + (r ^ (cl<<2)))*8);
    }
    #pragma unroll
    for (int m=0;m<WMT;m++)
      #pragma unroll
      for (int n=0;n<WNT;n++)
        acc[m][n] = __builtin_amdgcn_mfma_f32_16x16x32_bf16(af[m], bfv[n], acc[m][n], 0,0,0);
  }
  #pragma unroll
  for (int m=0;m<WMT;m++){
    int rbase = row0 + wm*WMT*16 + m*16 + (lane>>4)*4;
    #pragma unroll
    for (int n=0;n<WNT;n++){
      int col = col0 + wn*WNT*16 + n*16 + (lane&15);
      #pragma unroll
      for (int q=0;q<4;q++){
        int row = rbase + q;
        if (row < M) Cg[(size_t)row*N + col] = f2b(acc[m][n][q]);
      }
    }
  }
}

// ---------------- attention scores per node (vectorized) ----------------
__global__ void __launch_bounds__(256) k_asad(const unsigned short* __restrict__ Hn,
                                              const float* __restrict__ asw,
                                              const float* __restrict__ adw,
                                              float* __restrict__ as4,
                                              float* __restrict__ ad4){
  int wid = threadIdx.x>>6, lane = threadIdx.x&63;
  int n = blockIdx.x*4 + wid;
  if (n>=Nn) return;
  const ushort4 uv = *reinterpret_cast<const ushort4*>(Hn + (size_t)n*F + lane*4);
  const float4 wa = *reinterpret_cast<const float4*>(asw + lane*4);
  const float4 wd = *reinterpret_cast<const float4*>(adw + lane*4);
  float v0=b2f(uv.x), v1=b2f(uv.y), v2=b2f(uv.z), v3=b2f(uv.w);
  float ps = v0*wa.x + v1*wa.y + v2*wa.z + v3*wa.w;
  float pd = v0*wd.x + v1*wd.y + v2*wd.z + v3*wd.w;
  #pragma unroll
  for (int o=1;o<16;o<<=1){ ps += __shfl_xor(ps,o); pd += __shfl_xor(pd,o); }
  if ((lane&15)==0){
    int h = lane>>4;
    as4[(size_t)n*4+h]=ps; ad4[(size_t)n*4+h]=pd;
  }
}

// ---------------- single-pass GAT aggregation + bias + LN + ELU (layers 1,2) ----------------
__global__ void __launch_bounds__(256) k_agg(const unsigned short* __restrict__ Hs,
                                             const float* __restrict__ as4,
                                             const float* __restrict__ ad4,
                                             const float* __restrict__ bias,
                                             const float* __restrict__ gam,
                                             const float* __restrict__ bet,
                                             const int* __restrict__ off,
                                             const int* __restrict__ csr,
                                             unsigned short* __restrict__ out){
  int wid = threadIdx.x>>6, lane = threadIdx.x&63;
  int n = blockIdx.x*4 + wid;
  if (n>=Nn) return;
  int half = lane>>5, c8 = lane&31;       // channels c8*8 .. c8*8+7
  int h = c8>>3;
  float adh = ad4[(size_t)n*4 + h];
  const unsigned short* hbase = Hs + c8*8;
  int o0=off[n], o1=off[n+1];
  float a0=0,a1=0,a2=0,a3=0,a4=0,a5=0,a6=0,a7=0,den=0;
  int e = o0 + half;
  // 4 edges per half per iteration (8 edges in flight per wave)
  for (; e+6 < o1; e += 8){
    int s0v=csr[e], s1v=csr[e+2], s2v=csr[e+4], s3v=csr[e+6];
    float q0=as4[(size_t)s0v*4+h], q1=as4[(size_t)s1v*4+h],
          q2=as4[(size_t)s2v*4+h], q3=as4[(size_t)s3v*4+h];
    const ushort8v hv0 = *reinterpret_cast<const ushort8v*>(hbase + (size_t)s0v*F);
    const ushort8v hv1 = *reinterpret_cast<const ushort8v*>(hbase + (size_t)s1v*F);
    const ushort8v hv2 = *reinterpret_cast<const ushort8v*>(hbase + (size_t)s2v*F);
    const ushort8v hv3 = *reinterpret_cast<const ushort8v*>(hbase + (size_t)s3v*F);
    float t0=q0+adh; t0=t0>0.f?t0:0.2f*t0; float w0=__expf(t0);
    float t1=q1+adh; t1=t1>0.f?t1:0.2f*t1; float w1=__expf(t1);
    float t2=q2+adh; t2=t2>0.f?t2:0.2f*t2; float w2=__expf(t2);
    float t3=q3+adh; t3=t3>0.f?t3:0.2f*t3; float w3=__expf(t3);
    den += (w0+w1)+(w2+w3);
    a0 += w0*b2f(hv0[0]) + w1*b2f(hv1[0]) + w2*b2f(hv2[0]) + w3*b2f(hv3[0]);
    a1 += w0*b2f(hv0[1]) + w1*b2f(hv1[1]) + w2*b2f(hv2[1]) + w3*b2f(hv3[1]);
    a2 += w0*b2f(hv0[2]) + w1*b2f(hv1[2]) + w2*b2f(hv2[2]) + w3*b2f(hv3[2]);
    a3 += w0*b2f(hv0[3]) + w1*b2f(hv1[3]) + w2*b2f(hv2[3]) + w3*b2f(hv3[3]);
    a4 += w0*b2f(hv0[4]) + w1*b2f(hv1[4]) + w2*b2f(hv2[4]) + w3*b2f(hv3[4]);
    a5 += w0*b2f(hv0[5]) + w1*b2f(hv1[5]) + w2*b2f(hv2[5]) + w3*b2f(hv3[5]);
    a6 += w0*b2f(hv0[6]) + w1*b2f(hv1[6]) + w2*b2f(hv2[6]) + w3*b2f(hv3[6]);
    a7 += w0*b2f(hv0[7]) + w1*b2f(hv1[7]) + w2*b2f(hv2[7]) + w3*b2f(hv3[7]);
  }
  for (; e < o1; e += 2){
    int sv=csr[e];
    float q=as4[(size_t)sv*4+h];
    float t=q+adh; t=t>0.f?t:0.2f*t; float w=__expf(t);
    const ushort8v hv = *reinterpret_cast<const ushort8v*>(hbase + (size_t)sv*F);
    den += w;
    a0 += w*b2f(hv[0]); a1 += w*b2f(hv[1]); a2 += w*b2f(hv[2]); a3 += w*b2f(hv[3]);
    a4 += w*b2f(hv[4]); a5 += w*b2f(hv[5]); a6 += w*b2f(hv[6]); a7 += w*b2f(hv[7]);
  }
  // combine half-waves
  a0 += __shfl_xor(a0,32); a1 += __shfl_xor(a1,32);
  a2 += __shfl_xor(a2,32); a3 += __shfl_xor(a3,32);
  a4 += __shfl_xor(a4,32); a5 += __shfl_xor(a5,32);
  a6 += __shfl_xor(a6,32); a7 += __shfl_xor(a7,32);
  den += __shfl_xor(den,32);
  float rs = 1.f/(den + 1e-16f);
  // normalize + bias
  int c = c8*8;
  const float4 bv0 = *reinterpret_cast<const float4*>(bias + c);
  const float4 bv1 = *reinterpret_cast<const float4*>(bias + c + 4);
  a0=a0*rs+bv0.x; a1=a1*rs+bv0.y; a2=a2*rs+bv0.z; a3=a3*rs+bv0.w;
  a4=a4*rs+bv1.x; a5=a5*rs+bv1.y; a6=a6*rs+bv1.z; a7=a7*rs+bv1.w;
  // LayerNorm over 256 (values duplicated across halves -> /512)
  float sl = a0+a1+a2+a3+a4+a5+a6+a7;
  float mu = wsum64(sl)*(1.f/512.f);
  float d0=a0-mu,d1=a1-mu,d2=a2-mu,d3=a3-mu,d4=a4-mu,d5=a5-mu,d6=a6-mu,d7=a7-mu;
  float ql = d0*d0+d1*d1+d2*d2+d3*d3+d4*d4+d5*d5+d6*d6+d7*d7;
  float var = wsum64(ql)*(1.f/512.f);
  float r = rsqrtf(var + 1e-5f);
  const float4 gv0 = *reinterpret_cast<const float4*>(gam + c);
  const float4 gv1 = *reinterpret_cast<const float4*>(gam + c + 4);
  const float4 ev0 = *reinterpret_cast<const float4*>(bet + c);
  const float4 ev1 = *reinterpret_cast<const float4*>(bet + c + 4);
  float y0=d0*r*gv0.x+ev0.x, y1=d1*r*gv0.y+ev0.y, y2=d2*r*gv0.z+ev0.z, y3=d3*r*gv0.w+ev0.w;
  float y4=d4*r*gv1.x+ev1.x, y5=d5*r*gv1.y+ev1.y, y6=d6*r*gv1.z+ev1.z, y7=d7*r*gv1.w+ev1.w;
  y0=y0>0.f?y0:expm1f(y0); y1=y1>0.f?y1:expm1f(y1);
  y2=y2>0.f?y2:expm1f(y2); y3=y3>0.f?y3:expm1f(y3);
  y4=y4>0.f?y4:expm1f(y4); y5=y5>0.f?y5:expm1f(y5);
  y6=y6>0.f?y6:expm1f(y6); y7=y7>0.f?y7:expm1f(y7);
  if (half==0){
    ushort8v ov;
    ov[0]=f2b(y0); ov[1]=f2b(y1); ov[2]=f2b(y2); ov[3]=f2b(y3);
    ov[4]=f2b(y4); ov[5]=f2b(y5); ov[6]=f2b(y6); ov[7]=f2b(y7);
    *reinterpret_cast<ushort8v*>(out + (size_t)n*F + c) = ov;
  }
}

// ---------------- layer 3 scores ----------------
__global__ void __launch_bounds__(256) k_asad3(const unsigned short* __restrict__ C3,
                                               const float* __restrict__ asw,
                                               const float* __restrict__ adw,
                                               float* __restrict__ s3,
                                               float* __restrict__ d3){
  int wid=threadIdx.x>>6, lane=threadIdx.x&63;
  int n = blockIdx.x*4 + wid;
  if (n>=Nn) return;
  float v = (lane<32) ? b2f(C3[(long)n*DO + lane]) : 0.f;
  float wa = (lane<32) ? asw[lane] : 0.f;
  float wd = (lane<32) ? adw[lane] : 0.f;
  float ps = wsum64(v*wa);
  float pd = wsum64(v*wd);
  if (lane==0){ s3[n]=ps; d3[n]=pd; }
}

// ---------------- layer 3 single-pass aggregation (8 lanes/edge) ----------------
__global__ void __launch_bounds__(256) k_agg3(const unsigned short* __restrict__ C3,
                                              const float* __restrict__ s3,
                                              const float* __restrict__ d3,
                                              const float* __restrict__ b3,
                                              const int* __restrict__ off,
                                              const int* __restrict__ csr,
                                              float* __restrict__ h3f,
                                              void* __restrict__ dout,
                                              const int* __restrict__ flagp){
  int wid=threadIdx.x>>6, lane=threadIdx.x&63;
  int n = blockIdx.x*4 + wid;
  if (n>=Nn) return;
  int bf = *flagp;
  int grp = lane>>3, j = lane&7;          // 8 groups x 8 lanes; channels j*4..j*4+3
  float dn = d3[n];
  int o0=off[n], o1=off[n+1];
  float a0=0,a1=0,a2=0,a3=0,den=0;
  for (int e=o0+grp; e<o1; e+=8){
    int s=csr[e];
    float t=s3[s]+dn; t=t>0.f?t:0.2f*t;
    float w=__expf(t);
    const ushort4 hv = *reinterpret_cast<const ushort4*>(C3 + (size_t)s*DO + j*4);
    den += w;
    a0 += w*b2f(hv.x); a1 += w*b2f(hv.y); a2 += w*b2f(hv.z); a3 += w*b2f(hv.w);
  }
  #pragma unroll
  for (int o=8;o<64;o<<=1){
    a0 += __shfl_xor(a0,o); a1 += __shfl_xor(a1,o);
    a2 += __shfl_xor(a2,o); a3 += __shfl_xor(a3,o);
    den += __shfl_xor(den,o);
  }
  if (lane<8){
    float rs = 1.f/(den + 1e-16f);
    int c = lane*4;
    const float4 bv = *reinterpret_cast<const float4*>(b3 + c);
    float v0=a0*rs+bv.x, v1=a1*rs+bv.y, v2=a2*rs+bv.z, v3=a3*rs+bv.w;
    float4 o4; o4.x=v0; o4.y=v1; o4.z=v2; o4.w=v3;
    *reinterpret_cast<float4*>(h3f + (size_t)n*DO + c) = o4;
    long bo = (long)n*DO + c;
    st_out(dout, bf, bo  , v0);
    st_out(dout, bf, bo+1, v1);
    st_out(dout, bf, bo+2, v2);
    st_out(dout, bf, bo+3, v3);
  }
}

// ---------------- risk head ----------------
__global__ void __launch_bounds__(256) k_risk(const float* __restrict__ h3f,
                                              const float* __restrict__ wf,
                                              void* __restrict__ dout,
                                              const int* __restrict__ flagp){
  int n = blockIdx.x*256 + threadIdx.x;
  if (n>=Nn) return;
  int bf = *flagp;
  float hv[32];
  #pragma unroll
  for (int k=0;k<32;k++) hv[k]=h3f[(long)n*32+k];
  float t1[32];
  #pragma unroll
  for (int j=0;j<32;j++){
    float s = wf[BR1O+j];
    #pragma unroll
    for (int k=0;k<32;k++) s += hv[k]*wf[WR1O+k*32+j];
    t1[j] = fmaxf(s,0.f);
  }
  #pragma unroll
  for (int o=0;o<6;o++){
    float s = wf[BR2O+o];
    #pragma unroll
    for (int j=0;j<32;j++) s += t1[j]*wf[WR2O+j*6+o];
    float r = 1.f/(1.f+expf(-s));
    st_out(dout, bf, (long)Nn*32 + (long)n*6 + o, r);
  }
}

// ---------------- launcher ----------------
extern "C" void kernel_launch(void* const* d_in, const int* in_sizes, int n_in,
                              void* d_out, int out_size, void* d_ws, size_t ws_size,
                              hipStream_t stream){
  char* base = (char*)d_ws;
  size_t cur = 0;
  auto alloc = [&](size_t bytes)->char*{
    cur = (cur + 255) & ~(size_t)255;
    char* r = base + cur; cur += bytes; return r;
  };
  int*   flag = (int*)  alloc(4);
  float* wf   = (float*)alloc(sizeof(float)*WTOT);
  unsigned short* xpad = (unsigned short*)alloc(sizeof(short)*(size_t)Np*32);
  unsigned short* w1t = (unsigned short*)alloc(sizeof(short)*256*32);
  unsigned short* w2t = (unsigned short*)alloc(sizeof(short)*256*256);
  unsigned short* w3t = (unsigned short*)alloc(sizeof(short)*32*256);
  int*   deg  = (int*)  alloc(sizeof(int)*Nn);
  int*   offt = (int*)  alloc(sizeof(int)*Nn);
  int*   bsum = (int*)  alloc(sizeof(int)*256);
  int*   bpre = (int*)  alloc(sizeof(int)*256);
  int*   off  = (int*)  alloc(sizeof(int)*(Nn+1));
  int*   curs = (int*)  alloc(sizeof(int)*Nn);
  int*   csr  = (int*)  alloc(sizeof(int)*ET);
  unsigned short* G  = (unsigned short*)alloc(sizeof(short)*(size_t)Np*F);
  unsigned short* Hb = (unsigned short*)alloc(sizeof(short)*(size_t)Np*F);
  unsigned short* C3 = (unsigned short*)alloc(sizeof(short)*(size_t)Np*DO);
  float* as4  = (float*)alloc(sizeof(float)*(size_t)Nn*4);
  float* ad4  = (float*)alloc(sizeof(float)*(size_t)Nn*4);
  float* s3   = (float*)alloc(sizeof(float)*Nn);
  float* d3   = (float*)alloc(sizeof(float)*Nn);
  float* h3f  = (float*)alloc(sizeof(float)*(size_t)Nn*DO);

  const int* ei = (const int*)d_in[1];
  InPtrs ip;
  for (int i=0;i<22;i++) ip.p[i]=d_in[i];

  k_detect<<<1,256,0,stream>>>((const unsigned*)d_in[0], flag);
  k_convert<<<16,256,0,stream>>>(ip, wf, flag);
  k_xpad<<<(Np*32+255)/256,256,0,stream>>>(d_in[0], xpad, flag);
  k_w1t<<<32,256,0,stream>>>(d_in[2], w1t, flag);
  k_w2t<<<256,256,0,stream>>>(d_in[6], w2t, flag);
  k_w3t<<<32,256,0,stream>>>(d_in[10], w3t, flag);

  (void)hipMemsetAsync(deg, 0, sizeof(int)*Nn, stream);
  k_count<<<(Ee+255)/256,256,0,stream>>>(ei, deg);
  k_scan_blk<<<196,256,0,stream>>>(deg, offt, bsum);
  k_scan_top<<<1,256,0,stream>>>(bsum, bpre, off);
  k_scan_add<<<196,256,0,stream>>>(offt, bpre, off, curs);
  k_fill<<<(ET+255)/256,256,0,stream>>>(ei, curs, csr);

  dim3 wg((Nn+3)/4);
  constexpr int nMB = (Nn + 127)/128;   // 391
  // layer 1 (MFMA, K=32 zero-padded)
  k_gemm_mfma<128,128,2,2,32><<<nMB*2,256,0,stream>>>(xpad, w1t, G, Nn, 256, nMB);
  k_asad <<<wg,256,0,stream>>>(G, wf+A1S, wf+A1D, as4, ad4);
  k_agg  <<<wg,256,0,stream>>>(G, as4, ad4, wf+B1O, wf+G1O, wf+BE1O, off, csr, Hb);
  // layer 2
  k_gemm_mfma<128,128,2,2,256><<<nMB*2,256,0,stream>>>(Hb, w2t, G, Nn, 256, nMB);
  k_asad <<<wg,256,0,stream>>>(G, wf+A2S, wf+A2D, as4, ad4);
  k_agg  <<<wg,256,0,stream>>>(G, as4, ad4, wf+B2O, wf+G2O, wf+BE2O, off, csr, Hb);
  // layer 3
  k_gemm_mfma<128,32,4,1,256><<<nMB,256,0,stream>>>(Hb, w3t, C3, Nn, 32, nMB);
  k_asad3<<<wg,256,0,stream>>>(C3, wf+A3S, wf+A3D, s3, d3);
  k_agg3 <<<wg,256,0,stream>>>(C3, s3, d3, wf+B3O, off, csr, h3f, d_out, flag);
  k_risk <<<(Nn+255)/256,256,0,stream>>>(h3f, wf, d_out, flag);
}